// Round 9
// baseline (222.593 us; speedup 1.0000x reference)
//
#include <hip/hip_runtime.h>
#include <stdint.h>

#define H_DIM 1024
#define B_DIM 16384

typedef unsigned short u16;
typedef short bf16x8 __attribute__((ext_vector_type(8)));
typedef unsigned short ushort8 __attribute__((ext_vector_type(8)));
typedef float f32x4 __attribute__((ext_vector_type(4)));

__device__ __forceinline__ u16 f2bf(float f) {
  union { float f; uint32_t u; } v; v.f = f;
  uint32_t r = v.u + 0x7fffu + ((v.u >> 16) & 1u);
  return (u16)(r >> 16);
}
__device__ __forceinline__ float bf2f(u16 x) {
  union { uint32_t u; float f; } v; v.u = ((uint32_t)x) << 16;
  return v.f;
}

// 8 fp32 -> bf16x8 via v_cvt_pk_bf16_f32 (RNE, gfx950 inline asm).
__device__ __forceinline__ bf16x8 cvt8(float4 a, float4 b) {
  union { uint32_t u[4]; bf16x8 v; } r;
  asm("v_cvt_pk_bf16_f32 %0, %1, %2" : "=v"(r.u[0]) : "v"(a.x), "v"(a.y));
  asm("v_cvt_pk_bf16_f32 %0, %1, %2" : "=v"(r.u[1]) : "v"(a.z), "v"(a.w));
  asm("v_cvt_pk_bf16_f32 %0, %1, %2" : "=v"(r.u[2]) : "v"(b.x), "v"(b.y));
  asm("v_cvt_pk_bf16_f32 %0, %1, %2" : "=v"(r.u[3]) : "v"(b.z), "v"(b.w));
  return r.v;
}

#define GLDS16(gsrc, ldst)                                                                 \
  __builtin_amdgcn_global_load_lds((const __attribute__((address_space(1))) void*)(gsrc),  \
                                   (__attribute__((address_space(3))) void*)(ldst), 16, 0, 0)

// ---------------- weight-only cvt (w1, pm_w, Wrec) + rtau ----------------------------------
__device__ __forceinline__ void cvt_region(const float* __restrict__ in, u16* __restrict__ out,
                                           int tid, int nthr, int ngroups) {
  const float4* in4 = (const float4*)in;
  ushort8* out8 = (ushort8*)out;
  for (int gi = tid; gi < ngroups; gi += nthr) {
    float4 a = in4[2 * gi];
    float4 b = in4[2 * gi + 1];
    ushort8 o;
    o[0] = f2bf(a.x); o[1] = f2bf(a.y); o[2] = f2bf(a.z); o[3] = f2bf(a.w);
    o[4] = f2bf(b.x); o[5] = f2bf(b.y); o[6] = f2bf(b.z); o[7] = f2bf(b.w);
    out8[gi] = o;
  }
}

__global__ __launch_bounds__(256) void cvt_w(const float* __restrict__ w1f,
                                             const float* __restrict__ pmwf,
                                             const float* __restrict__ wrecf,
                                             u16* __restrict__ o1, u16* __restrict__ o3,
                                             u16* __restrict__ o4,
                                             const float* __restrict__ tau,
                                             float* __restrict__ rtau) {
  const int b = blockIdx.x;
  const int HH8 = (H_DIM * H_DIM) / 8;
  if (b < 256) {
    cvt_region(w1f, o1, b * 256 + threadIdx.x, 256 * 256, HH8);
  } else if (b < 512) {
    cvt_region(pmwf, o3, (b - 256) * 256 + threadIdx.x, 256 * 256, HH8);
  } else if (b < 768) {
    cvt_region(wrecf, o4, (b - 512) * 256 + threadIdx.x, 256 * 256, HH8);
  } else {
    for (int i = threadIdx.x; i < H_DIM; i += 256) rtau[i] = 1.0f / tau[i];
  }
}

// ---------------- transpose-cvt of ce_w2 (r7-verified) --------------------------------------
__global__ __launch_bounds__(256) void tr_cvt_w2(const float* __restrict__ in,
                                                 u16* __restrict__ out) {
  __shared__ float tile[64][65];
  const int t = threadIdx.x;
  const int r0 = (blockIdx.x >> 4) * 64;
  const int c0 = (blockIdx.x & 15) * 64;
  const float4* in4 = (const float4*)in;
#pragma unroll
  for (int it = 0; it < 4; ++it) {
    const int idx = it * 256 + t;
    const int r = idx >> 4, c4 = idx & 15;
    float4 v = in4[(size_t)(r0 + r) * 256 + (c0 >> 2) + c4];
    tile[r][c4 * 4 + 0] = v.x; tile[r][c4 * 4 + 1] = v.y;
    tile[r][c4 * 4 + 2] = v.z; tile[r][c4 * 4 + 3] = v.w;
  }
  __syncthreads();
  ushort4* out4 = (ushort4*)out;
#pragma unroll
  for (int it = 0; it < 4; ++it) {
    const int idx = it * 256 + t;
    const int c = idx >> 4, r4 = idx & 15;
    ushort4 o;
    o.x = f2bf(tile[r4 * 4 + 0][c]); o.y = f2bf(tile[r4 * 4 + 1][c]);
    o.z = f2bf(tile[r4 * 4 + 2][c]); o.w = f2bf(tile[r4 * 4 + 3][c]);
    out4[(size_t)(c0 + c) * 256 + (r0 >> 2) + r4] = o;
  }
}

// ---------------- b32[i] = dot(pm_w[i,:], ce_b2) + pm_b[i] (r7-verified) --------------------
__global__ __launch_bounds__(256) void b32_prep(const float* __restrict__ pmw,
                                                const float* __restrict__ ceb2,
                                                const float* __restrict__ pmb,
                                                float* __restrict__ b32) {
  const int i = blockIdx.x * 256 + threadIdx.x;
  const float4* w4 = (const float4*)(pmw + (size_t)i * H_DIM);
  const float4* b4 = (const float4*)ceb2;
  float acc = pmb[i];
  for (int k = 0; k < 256; ++k) {
    float4 w = w4[k], b = b4[k];
    acc += w.x * b.x + w.y * b.y + w.z * b.z + w.w * b.w;
  }
  b32[i] = acc;
}

// ---------------- W32 = pm_w @ ce_w2 (1024^3, r7-verified) ----------------------------------
__global__ __launch_bounds__(256) void w32_gemm(const u16* __restrict__ A,
                                                const u16* __restrict__ Wt,
                                                u16* __restrict__ C) {
  const int t = threadIdx.x;
  const int wv = t >> 6, l = t & 63;
  const int l15 = l & 15, lg = l >> 4;
  const int m0 = (blockIdx.x >> 4) * 64 + (wv >> 1) * 32;
  const int n0 = (blockIdx.x & 15) * 64 + (wv & 1) * 32;

  const u16* ap0 = A + (size_t)(m0 + l15) * H_DIM + lg * 8;
  const u16* ap1 = ap0 + 16 * H_DIM;
  const u16* bp0 = Wt + (size_t)(n0 + l15) * H_DIM + lg * 8;
  const u16* bp1 = bp0 + 16 * H_DIM;

  f32x4 acc[2][2] = {};
#pragma unroll
  for (int kt = 0; kt < 32; ++kt) {
    bf16x8 aF[2], bF[2];
    aF[0] = *(const bf16x8*)(ap0 + kt * 32);
    aF[1] = *(const bf16x8*)(ap1 + kt * 32);
    bF[0] = *(const bf16x8*)(bp0 + kt * 32);
    bF[1] = *(const bf16x8*)(bp1 + kt * 32);
#pragma unroll
    for (int mi = 0; mi < 2; ++mi)
#pragma unroll
      for (int ni = 0; ni < 2; ++ni)
        acc[mi][ni] =
            __builtin_amdgcn_mfma_f32_16x16x32_bf16(aF[mi], bF[ni], acc[mi][ni], 0, 0, 0);
  }
#pragma unroll
  for (int mi = 0; mi < 2; ++mi)
#pragma unroll
    for (int ni = 0; ni < 2; ++ni) {
      const int col = n0 + ni * 16 + l15;
#pragma unroll
      for (int j = 0; j < 4; ++j) {
        const int row = m0 + mi * 16 + lg * 4 + j;
        C[(size_t)row * H_DIM + col] = f2bf(acc[mi][ni][j]);
      }
    }
}

// ---------------- bf16-A 256x256 deep-pipelined GEMM (r4-verified, Gpa) ---------------------
template <int MODE>
__device__ __forceinline__ void subtile_step(u16* shp, int slot, int slot3, int aoff, int boff,
                                             int wv, const u16*& pA0, const u16*& pA1,
                                             const u16*& pB0, const u16*& pB1,
                                             f32x4 (&acc)[8][4]) {
  const u16* Ab = shp + slot * 16384 + aoff;
  const u16* Bb = shp + slot * 16384 + 8192 + boff;
  bf16x8 aF[8], bF[4];
#pragma unroll
  for (int i = 0; i < 4; ++i) aF[i] = *(const bf16x8*)(Ab + i * 512);
#pragma unroll
  for (int i = 0; i < 4; ++i) bF[i] = *(const bf16x8*)(Bb + i * 512);
#pragma unroll
  for (int i = 4; i < 8; ++i) aF[i] = *(const bf16x8*)(Ab + i * 512);
  if (MODE == 3) {
    u16* da = shp + slot3 * 16384 + wv * 1024;
    GLDS16(pA0, da); GLDS16(pA1, da + 512);
    u16* db = shp + slot3 * 16384 + 8192 + wv * 1024;
    GLDS16(pB0, db); GLDS16(pB1, db + 512);
    pA0 += 32; pA1 += 32; pB0 += 32; pB1 += 32;
  }
  __builtin_amdgcn_s_setprio(1);
#pragma unroll
  for (int mf = 0; mf < 8; ++mf)
#pragma unroll
    for (int nf = 0; nf < 4; ++nf)
      acc[mf][nf] = __builtin_amdgcn_mfma_f32_16x16x32_bf16(aF[mf], bF[nf], acc[mf][nf], 0, 0, 0);
  __builtin_amdgcn_s_setprio(0);
  if (MODE == 3) asm volatile("s_waitcnt vmcnt(8)" ::: "memory");
  if (MODE == 2) asm volatile("s_waitcnt vmcnt(4)" ::: "memory");
  if (MODE == 1) asm volatile("s_waitcnt vmcnt(0)" ::: "memory");
  __builtin_amdgcn_s_barrier();
}

template <bool RELU, bool HASBIAS, typename OUT>
__global__ __launch_bounds__(512, 2) void gemm256(const u16* __restrict__ A,
                                                  const u16* __restrict__ W,
                                                  const float* __restrict__ bias,
                                                  OUT* __restrict__ C) {
  extern __shared__ u16 sh[];
  const int t = threadIdx.x;
  const int wv = t >> 6, l = t & 63;
  const int wm = wv >> 2, wn = wv & 3;
  const int l15 = l & 15, lg = l >> 4;

  const int bid = blockIdx.x;
  const int logical = (bid & 7) * 32 + (bid >> 3);
  const int m0 = (logical >> 2) * 256;
  const int n0 = (logical & 3) * 256;

  const int koff = (lg ^ ((l15 >> 1) & 3)) * 8;
  const int aoff = (wm * 128 + l15) * 32 + koff;
  const int boff = (wn * 64 + l15) * 32 + koff;

  const int rowst = wv * 32 + (l >> 2);
  const int ksl = ((l & 3) ^ ((l >> 3) & 3)) * 8;
  const u16* pA0 = A + (size_t)(m0 + rowst) * H_DIM + ksl;
  const u16* pA1 = pA0 + 16 * H_DIM;
  const u16* pB0 = W + (size_t)(n0 + rowst) * H_DIM + ksl;
  const u16* pB1 = pB0 + 16 * H_DIM;

  f32x4 acc[8][4] = {};

#pragma unroll
  for (int s = 0; s < 3; ++s) {
    u16* da = sh + s * 16384 + wv * 1024;
    GLDS16(pA0, da); GLDS16(pA1, da + 512);
    u16* db = sh + s * 16384 + 8192 + wv * 1024;
    GLDS16(pB0, db); GLDS16(pB1, db + 512);
    pA0 += 32; pA1 += 32; pB0 += 32; pB1 += 32;
  }
  asm volatile("s_waitcnt vmcnt(8)" ::: "memory");
  __builtin_amdgcn_s_barrier();

  for (int s = 0; s < 29; ++s)
    subtile_step<3>(sh, s & 3, (s + 3) & 3, aoff, boff, wv, pA0, pA1, pB0, pB1, acc);
  subtile_step<2>(sh, 1, 0, aoff, boff, wv, pA0, pA1, pB0, pB1, acc);
  subtile_step<1>(sh, 2, 0, aoff, boff, wv, pA0, pA1, pB0, pB1, acc);
  subtile_step<0>(sh, 3, 0, aoff, boff, wv, pA0, pA1, pB0, pB1, acc);

  float bv[4];
#pragma unroll
  for (int nf = 0; nf < 4; ++nf)
    bv[nf] = HASBIAS ? bias[n0 + wn * 64 + nf * 16 + l15] : 0.0f;
#pragma unroll
  for (int mf = 0; mf < 8; ++mf) {
#pragma unroll
    for (int nf = 0; nf < 4; ++nf) {
      const int col = n0 + wn * 64 + nf * 16 + l15;
#pragma unroll
      for (int j = 0; j < 4; ++j) {
        const int row = m0 + wm * 128 + mf * 16 + lg * 4 + j;
        float v = acc[mf][nf][j] + bv[nf];
        if (RELU) v = fmaxf(v, 0.0f);
        if constexpr (sizeof(OUT) == 2)
          C[(size_t)row * H_DIM + col] = (OUT)f2bf(v);
        else
          C[(size_t)row * H_DIM + col] = v;
      }
    }
  }
}

// ---------------- fp32-A GEMM, reg-staged cvt (T14 minimal) ---------------------------------
// LDS layout/read path BIT-IDENTICAL to gemm256 (measured 0-conflict). A converted in regs:
// per thread per subtile: 4x float4 global loads (64B/row coalesced) -> 2x cvt8 ->
// 2x ds_write_b128 into the same swizzled slots gload_lds would produce.
// Ledger: issue/subtile = {4 A-loads(s+2), 2 B-gloads(s+2)}. Mid vmcnt(2) retires A-regs(s-1)
// before ds_write A(s+1); end vmcnt(6) retires B(s+1). Tail: s30 vmcnt(2)/vmcnt(0); s31 pure.
// Reg-dep correctness double-covered by compiler auto-waits on the float4 loads.
template <int SLOT, int MODE>  // MODE 2=steady, 1=s30 (write only), 0=s31 (pure)
__device__ __forceinline__ void step_f32r(u16* sh, int aoff, int boff, int wv, int dw0,
                                          const float*& gA0, const float*& gA1,
                                          const u16*& pB0, const u16*& pB1,
                                          float4 (&setW)[4], float4 (&setL)[4],
                                          f32x4 (&acc)[8][4]) {
  const u16* Ab = sh + SLOT * 16384 + aoff;
  const u16* Bb = sh + SLOT * 16384 + 8192 + boff;
  bf16x8 aF[8], bF[4];
#pragma unroll
  for (int i = 0; i < 4; ++i) aF[i] = *(const bf16x8*)(Ab + i * 512);
#pragma unroll
  for (int i = 0; i < 4; ++i) bF[i] = *(const bf16x8*)(Bb + i * 512);
#pragma unroll
  for (int i = 4; i < 8; ++i) aF[i] = *(const bf16x8*)(Ab + i * 512);
  if (MODE >= 1) {
    asm volatile("s_waitcnt vmcnt(2)" ::: "memory");
    u16* wb = sh + ((SLOT + 1) & 3) * 16384;
    *(bf16x8*)(wb + dw0) = cvt8(setW[0], setW[1]);
    *(bf16x8*)(wb + dw0 + 4096) = cvt8(setW[2], setW[3]);
  }
  if (MODE == 2) {
    setL[0] = *(const float4*)(gA0);
    setL[1] = *(const float4*)(gA0 + 4);
    setL[2] = *(const float4*)(gA1);
    setL[3] = *(const float4*)(gA1 + 4);
    gA0 += 32; gA1 += 32;
    u16* db = sh + ((SLOT + 2) & 3) * 16384 + 8192 + wv * 1024;
    GLDS16(pB0, db); GLDS16(pB1, db + 512);
    pB0 += 32; pB1 += 32;
  }
  __builtin_amdgcn_s_setprio(1);
#pragma unroll
  for (int mf = 0; mf < 8; ++mf)
#pragma unroll
    for (int nf = 0; nf < 4; ++nf)
      acc[mf][nf] = __builtin_amdgcn_mfma_f32_16x16x32_bf16(aF[mf], bF[nf], acc[mf][nf], 0, 0, 0);
  __builtin_amdgcn_s_setprio(0);
  if (MODE == 2) asm volatile("s_waitcnt vmcnt(6)" ::: "memory");
  if (MODE == 1) asm volatile("s_waitcnt vmcnt(0)" ::: "memory");
  asm volatile("s_waitcnt lgkmcnt(0)" ::: "memory");
  __builtin_amdgcn_s_barrier();
}

template <bool RELU, bool HASBIAS>
__global__ __launch_bounds__(512, 1) void gemm256_f32r(const float* __restrict__ A,
                                                       const u16* __restrict__ W,
                                                       const float* __restrict__ bias,
                                                       u16* __restrict__ C) {
  extern __shared__ u16 sh[];
  const int t = threadIdx.x;
  const int wv = t >> 6, l = t & 63;
  const int wm = wv >> 2, wn = wv & 3;
  const int l15 = l & 15, lg = l >> 4;

  const int bid = blockIdx.x;
  const int logical = (bid & 7) * 32 + (bid >> 3);
  const int m0 = (logical >> 2) * 256;
  const int n0 = (logical & 3) * 256;

  const int koff = (lg ^ ((l15 >> 1) & 3)) * 8;
  const int aoff = (wm * 128 + l15) * 32 + koff;
  const int boff = (wn * 64 + l15) * 32 + koff;

  // A reg-stage: thread -> rows {rbase, rbase+128}, 16B-slot s4 (8 floats each row).
  const int rbase = t >> 2;
  const int s4 = t & 3;
  const int dw0 = rbase * 32 + (s4 ^ ((rbase >> 1) & 3)) * 8;  // u16 offset; +4096 for row+128
  const float* gA0 = A + (size_t)(m0 + rbase) * H_DIM + s4 * 8;
  const float* gA1 = gA0 + (size_t)128 * H_DIM;

  // B stage source (gemm256 pattern).
  const int rowst = wv * 32 + (l >> 2);
  const int ksl = ((l & 3) ^ ((l >> 3) & 3)) * 8;
  const u16* pB0 = W + (size_t)(n0 + rowst) * H_DIM + ksl;
  const u16* pB1 = pB0 + 16 * H_DIM;

  f32x4 acc[8][4] = {};
  float4 sE[4], sO[4];

  // Prologue: A(0)->sE, A(1)->sO, B slots 0,1; write A(0)->slot0.
  sE[0] = *(const float4*)(gA0); sE[1] = *(const float4*)(gA0 + 4);
  sE[2] = *(const float4*)(gA1); sE[3] = *(const float4*)(gA1 + 4);
  gA0 += 32; gA1 += 32;
  sO[0] = *(const float4*)(gA0); sO[1] = *(const float4*)(gA0 + 4);
  sO[2] = *(const float4*)(gA1); sO[3] = *(const float4*)(gA1 + 4);
  gA0 += 32; gA1 += 32;
#pragma unroll
  for (int s = 0; s < 2; ++s) {
    u16* db = sh + s * 16384 + 8192 + wv * 1024;
    GLDS16(pB0, db); GLDS16(pB1, db + 512);
    pB0 += 32; pB1 += 32;
  }
  asm volatile("s_waitcnt vmcnt(4)" ::: "memory");  // all 8 A-loads done
  *(bf16x8*)(sh + dw0) = cvt8(sE[0], sE[1]);
  *(bf16x8*)(sh + dw0 + 4096) = cvt8(sE[2], sE[3]);
  asm volatile("s_waitcnt vmcnt(2)" ::: "memory");  // B(0) done
  asm volatile("s_waitcnt lgkmcnt(0)" ::: "memory");
  __builtin_amdgcn_s_barrier();

  // s = 0..27 (7 x 4), 28, 29 steady; 30 write-only; 31 pure.
  for (int su = 0; su < 7; ++su) {
    step_f32r<0, 2>(sh, aoff, boff, wv, dw0, gA0, gA1, pB0, pB1, sO, sE, acc);
    step_f32r<1, 2>(sh, aoff, boff, wv, dw0, gA0, gA1, pB0, pB1, sE, sO, acc);
    step_f32r<2, 2>(sh, aoff, boff, wv, dw0, gA0, gA1, pB0, pB1, sO, sE, acc);
    step_f32r<3, 2>(sh, aoff, boff, wv, dw0, gA0, gA1, pB0, pB1, sE, sO, acc);
  }
  step_f32r<0, 2>(sh, aoff, boff, wv, dw0, gA0, gA1, pB0, pB1, sO, sE, acc);  // s=28
  step_f32r<1, 2>(sh, aoff, boff, wv, dw0, gA0, gA1, pB0, pB1, sE, sO, acc);  // s=29
  step_f32r<2, 1>(sh, aoff, boff, wv, dw0, gA0, gA1, pB0, pB1, sO, sE, acc);  // s=30
  step_f32r<3, 0>(sh, aoff, boff, wv, dw0, gA0, gA1, pB0, pB1, sE, sO, acc);  // s=31

  float bv[4];
#pragma unroll
  for (int nf = 0; nf < 4; ++nf)
    bv[nf] = HASBIAS ? bias[n0 + wn * 64 + nf * 16 + l15] : 0.0f;
#pragma unroll
  for (int mf = 0; mf < 8; ++mf) {
#pragma unroll
    for (int nf = 0; nf < 4; ++nf) {
      const int col = n0 + wn * 64 + nf * 16 + l15;
#pragma unroll
      for (int j = 0; j < 4; ++j) {
        const int row = m0 + wm * 128 + mf * 16 + lg * 4 + j;
        float v = acc[mf][nf][j] + bv[nf];
        if (RELU) v = fmaxf(v, 0.0f);
        C[(size_t)row * H_DIM + col] = f2bf(v);
      }
    }
  }
}

// ---------------- fused liquid-neuron update + LayerNorm (h fp32, pa/ev bf16) ---------------
__global__ __launch_bounds__(256) void liquid_ln(const float* __restrict__ h,
                                                 const u16* __restrict__ pa,
                                                 const u16* __restrict__ ev,
                                                 const float* __restrict__ bias,
                                                 const float* __restrict__ rtau,
                                                 const float* __restrict__ decay,
                                                 const float* __restrict__ lnw,
                                                 const float* __restrict__ lnb,
                                                 float* __restrict__ out) {
  const int wv = threadIdx.x >> 6, l = threadIdx.x & 63;
  const int row = blockIdx.x * 4 + wv;
  const size_t rb = (size_t)row * H_DIM;

  float d[16];
  float s = 0.f, ss = 0.f;
#pragma unroll
  for (int c = 0; c < 2; ++c) {
    const int col = c * 512 + l * 8;
    float h8[8], b8[8], r8[8], dc8[8];
    *(float4*)h8 = *(const float4*)(h + rb + col);
    *(float4*)(h8 + 4) = *(const float4*)(h + rb + col + 4);
    *(float4*)b8 = *(const float4*)(bias + col);
    *(float4*)(b8 + 4) = *(const float4*)(bias + col + 4);
    *(float4*)r8 = *(const float4*)(rtau + col);
    *(float4*)(r8 + 4) = *(const float4*)(rtau + col + 4);
    *(float4*)dc8 = *(const float4*)(decay + col);
    *(float4*)(dc8 + 4) = *(const float4*)(decay + col + 4);
    ushort8 pv = *(const ushort8*)(pa + rb + col);
    ushort8 evv = *(const ushort8*)(ev + rb + col);
#pragma unroll
    for (int j = 0; j < 8; ++j) {
      const float p = bf2f(pv[j]);
      const float e = bf2f(evv[j]);
      const float num = fmaf(-dc8[j], h8[j], fmaf(1.0f + p, e, b8[j]));
      const float val = num * (1.0f + __expf(-p)) * r8[j];
      d[c * 8 + j] = val;
      s += val;
      ss += val * val;
    }
  }
#pragma unroll
  for (int off = 32; off; off >>= 1) {
    s += __shfl_xor(s, off);
    ss += __shfl_xor(ss, off);
  }
  const float mu = s * (1.0f / H_DIM);
  const float var = ss * (1.0f / H_DIM) - mu * mu;
  const float rstd = rsqrtf(var + 1e-5f);

#pragma unroll
  for (int c = 0; c < 2; ++c) {
    const int col = c * 512 + l * 8;
    float w8[8], lb8[8], o[8];
    *(float4*)w8 = *(const float4*)(lnw + col);
    *(float4*)(w8 + 4) = *(const float4*)(lnw + col + 4);
    *(float4*)lb8 = *(const float4*)(lnb + col);
    *(float4*)(lb8 + 4) = *(const float4*)(lnb + col + 4);
#pragma unroll
    for (int j = 0; j < 8; ++j) o[j] = fmaf((d[c * 8 + j] - mu) * rstd, w8[j], lb8[j]);
    *(float4*)(out + rb + col) = *(float4*)o;
    *(float4*)(out + rb + col + 4) = *(float4*)(o + 4);
  }
}

extern "C" void kernel_launch(void* const* d_in, const int* in_sizes, int n_in,
                              void* d_out, int out_size, void* d_ws, size_t ws_size,
                              hipStream_t stream) {
  // setup_inputs order: t, h, e, W_rec, bias, tau, decay, ln_w, ln_b,
  //                     ce_w1, ce_b1, ce_w2, ce_b2, pm_w, pm_b
  const float* h = (const float*)d_in[1];
  const float* e = (const float*)d_in[2];
  const float* Wrec = (const float*)d_in[3];
  const float* bias = (const float*)d_in[4];
  const float* tau = (const float*)d_in[5];
  const float* decay = (const float*)d_in[6];
  const float* lnw = (const float*)d_in[7];
  const float* lnb = (const float*)d_in[8];
  const float* ce_w1 = (const float*)d_in[9];
  const float* ce_b1 = (const float*)d_in[10];
  const float* ce_w2 = (const float*)d_in[11];
  const float* ce_b2 = (const float*)d_in[12];
  const float* pm_w = (const float*)d_in[13];
  const float* pm_b = (const float*)d_in[14];
  float* out = (float*)d_out;

  char* ws = (char*)d_ws;
  const size_t MB = 1024 * 1024;
  // [0,2) w1b | [2,4) w2t | [4,6) w3b(pm_w) | [6,8) w4b(Wrec) | [8,10) W32b
  // [10,11) rtau @10MB, b32 @10MB+8KB | [12,44) t1 | [44,76) pab | [76,108) evb
  u16* w1b = (u16*)(ws + 0 * MB);
  u16* w2t = (u16*)(ws + 2 * MB);
  u16* w3b = (u16*)(ws + 4 * MB);
  u16* w4b = (u16*)(ws + 6 * MB);
  u16* W32b = (u16*)(ws + 8 * MB);
  float* rtau = (float*)(ws + 10 * MB);
  float* b32 = (float*)(ws + 10 * MB + 8192);
  u16* t1 = (u16*)(ws + 12 * MB);
  u16* pab = (u16*)(ws + 44 * MB);
  u16* evb = (u16*)(ws + 76 * MB);

  cvt_w<<<769, 256, 0, stream>>>(ce_w1, pm_w, Wrec, w1b, w3b, w4b, tau, rtau);
  tr_cvt_w2<<<256, 256, 0, stream>>>(ce_w2, w2t);
  b32_prep<<<4, 256, 0, stream>>>(pm_w, ce_b2, pm_b, b32);
  w32_gemm<<<256, 256, 0, stream>>>(w3b, w2t, W32b);

  const int LDS_BYTES = 131072;
  hipFuncSetAttribute((const void*)gemm256_f32r<true, true>,
                      hipFuncAttributeMaxDynamicSharedMemorySize, LDS_BYTES);
  hipFuncSetAttribute((const void*)gemm256_f32r<false, false>,
                      hipFuncAttributeMaxDynamicSharedMemorySize, LDS_BYTES);
  hipFuncSetAttribute((const void*)gemm256<false, true, u16>,
                      hipFuncAttributeMaxDynamicSharedMemorySize, LDS_BYTES);

  const int NWG = (B_DIM / 256) * (H_DIM / 256);  // 256 blocks = 1 per CU
  gemm256_f32r<true, true><<<NWG, 512, LDS_BYTES, stream>>>(h, w1b, ce_b1, t1);
  gemm256<false, true, u16><<<NWG, 512, LDS_BYTES, stream>>>(t1, W32b, b32, pab);
  gemm256_f32r<false, false><<<NWG, 512, LDS_BYTES, stream>>>(e, w4b, nullptr, evb);

  liquid_ln<<<B_DIM / 4, 256, 0, stream>>>(h, pab, evb, bias, rtau, decay, lnw, lnb, out);
}

// Round 10
// 222.353 us; speedup vs baseline: 1.0011x; 1.0011x over previous
//
#include <hip/hip_runtime.h>
#include <stdint.h>

#define H_DIM 1024
#define B_DIM 16384

typedef unsigned short u16;
typedef short bf16x8 __attribute__((ext_vector_type(8)));
typedef unsigned short ushort8 __attribute__((ext_vector_type(8)));
typedef float f32x4 __attribute__((ext_vector_type(4)));

__device__ __forceinline__ u16 f2bf(float f) {
  union { float f; uint32_t u; } v; v.f = f;
  uint32_t r = v.u + 0x7fffu + ((v.u >> 16) & 1u);
  return (u16)(r >> 16);
}
__device__ __forceinline__ float bf2f(u16 x) {
  union { uint32_t u; float f; } v; v.u = ((uint32_t)x) << 16;
  return v.f;
}

#define GLDS16(gsrc, ldst)                                                                 \
  __builtin_amdgcn_global_load_lds((const __attribute__((address_space(1))) void*)(gsrc),  \
                                   (__attribute__((address_space(3))) void*)(ldst), 16, 0, 0)

// ---------------- conversion: h, e, 3 weights, rtau in ONE dispatch (r7-measured 63 us) -----
__device__ __forceinline__ void cvt_region(const float* __restrict__ in, u16* __restrict__ out,
                                           int tid, int nthr, int ngroups) {
  const float4* in4 = (const float4*)in;
  ushort8* out8 = (ushort8*)out;
  for (int gi = tid; gi < ngroups; gi += nthr) {
    float4 a = in4[2 * gi];
    float4 b = in4[2 * gi + 1];
    ushort8 o;
    o[0] = f2bf(a.x); o[1] = f2bf(a.y); o[2] = f2bf(a.z); o[3] = f2bf(a.w);
    o[4] = f2bf(b.x); o[5] = f2bf(b.y); o[6] = f2bf(b.z); o[7] = f2bf(b.w);
    out8[gi] = o;
  }
}

__global__ __launch_bounds__(256) void cvt_all(const float* __restrict__ h,
                                               const float* __restrict__ e,
                                               const float* __restrict__ w1f,
                                               const float* __restrict__ pmwf,
                                               const float* __restrict__ wrecf,
                                               u16* __restrict__ hb, u16* __restrict__ eb,
                                               u16* __restrict__ o1, u16* __restrict__ o3,
                                               u16* __restrict__ o4,
                                               const float* __restrict__ tau,
                                               float* __restrict__ rtau) {
  const int b = blockIdx.x;
  const int BH8 = (B_DIM * H_DIM) / 8;
  const int HH8 = (H_DIM * H_DIM) / 8;
  if (b < 2048) {
    cvt_region(h, hb, b * 256 + threadIdx.x, 2048 * 256, BH8);
  } else if (b < 4096) {
    cvt_region(e, eb, (b - 2048) * 256 + threadIdx.x, 2048 * 256, BH8);
  } else if (b < 4352) {
    cvt_region(w1f, o1, (b - 4096) * 256 + threadIdx.x, 256 * 256, HH8);
  } else if (b < 4608) {
    cvt_region(pmwf, o3, (b - 4352) * 256 + threadIdx.x, 256 * 256, HH8);
  } else if (b < 4864) {
    cvt_region(wrecf, o4, (b - 4608) * 256 + threadIdx.x, 256 * 256, HH8);
  } else {
    for (int i = threadIdx.x; i < H_DIM; i += 256) rtau[i] = 1.0f / tau[i];
  }
}

// ---------------- transpose-cvt of ce_w2 (r7-verified) --------------------------------------
__global__ __launch_bounds__(256) void tr_cvt_w2(const float* __restrict__ in,
                                                 u16* __restrict__ out) {
  __shared__ float tile[64][65];
  const int t = threadIdx.x;
  const int r0 = (blockIdx.x >> 4) * 64;
  const int c0 = (blockIdx.x & 15) * 64;
  const float4* in4 = (const float4*)in;
#pragma unroll
  for (int it = 0; it < 4; ++it) {
    const int idx = it * 256 + t;
    const int r = idx >> 4, c4 = idx & 15;
    float4 v = in4[(size_t)(r0 + r) * 256 + (c0 >> 2) + c4];
    tile[r][c4 * 4 + 0] = v.x; tile[r][c4 * 4 + 1] = v.y;
    tile[r][c4 * 4 + 2] = v.z; tile[r][c4 * 4 + 3] = v.w;
  }
  __syncthreads();
  ushort4* out4 = (ushort4*)out;
#pragma unroll
  for (int it = 0; it < 4; ++it) {
    const int idx = it * 256 + t;
    const int c = idx >> 4, r4 = idx & 15;
    ushort4 o;
    o.x = f2bf(tile[r4 * 4 + 0][c]); o.y = f2bf(tile[r4 * 4 + 1][c]);
    o.z = f2bf(tile[r4 * 4 + 2][c]); o.w = f2bf(tile[r4 * 4 + 3][c]);
    out4[(size_t)(c0 + c) * 256 + (r0 >> 2) + r4] = o;
  }
}

// ---------------- b32[i] = dot(pm_w[i,:], ce_b2) + pm_b[i] (r7-verified) --------------------
__global__ __launch_bounds__(256) void b32_prep(const float* __restrict__ pmw,
                                                const float* __restrict__ ceb2,
                                                const float* __restrict__ pmb,
                                                float* __restrict__ b32) {
  const int i = blockIdx.x * 256 + threadIdx.x;
  const float4* w4 = (const float4*)(pmw + (size_t)i * H_DIM);
  const float4* b4 = (const float4*)ceb2;
  float acc = pmb[i];
  for (int k = 0; k < 256; ++k) {
    float4 w = w4[k], b = b4[k];
    acc += w.x * b.x + w.y * b.y + w.z * b.z + w.w * b.w;
  }
  b32[i] = acc;
}

// ---------------- W32 = pm_w @ ce_w2 (1024^3, r7-verified) ----------------------------------
__global__ __launch_bounds__(256) void w32_gemm(const u16* __restrict__ A,
                                                const u16* __restrict__ Wt,
                                                u16* __restrict__ C) {
  const int t = threadIdx.x;
  const int wv = t >> 6, l = t & 63;
  const int l15 = l & 15, lg = l >> 4;
  const int m0 = (blockIdx.x >> 4) * 64 + (wv >> 1) * 32;
  const int n0 = (blockIdx.x & 15) * 64 + (wv & 1) * 32;

  const u16* ap0 = A + (size_t)(m0 + l15) * H_DIM + lg * 8;
  const u16* ap1 = ap0 + 16 * H_DIM;
  const u16* bp0 = Wt + (size_t)(n0 + l15) * H_DIM + lg * 8;
  const u16* bp1 = bp0 + 16 * H_DIM;

  f32x4 acc[2][2] = {};
#pragma unroll
  for (int kt = 0; kt < 32; ++kt) {
    bf16x8 aF[2], bF[2];
    aF[0] = *(const bf16x8*)(ap0 + kt * 32);
    aF[1] = *(const bf16x8*)(ap1 + kt * 32);
    bF[0] = *(const bf16x8*)(bp0 + kt * 32);
    bF[1] = *(const bf16x8*)(bp1 + kt * 32);
#pragma unroll
    for (int mi = 0; mi < 2; ++mi)
#pragma unroll
      for (int ni = 0; ni < 2; ++ni)
        acc[mi][ni] =
            __builtin_amdgcn_mfma_f32_16x16x32_bf16(aF[mi], bF[ni], acc[mi][ni], 0, 0, 0);
  }
#pragma unroll
  for (int mi = 0; mi < 2; ++mi)
#pragma unroll
    for (int ni = 0; ni < 2; ++ni) {
      const int col = n0 + ni * 16 + l15;
#pragma unroll
      for (int j = 0; j < 4; ++j) {
        const int row = m0 + mi * 16 + lg * 4 + j;
        C[(size_t)row * H_DIM + col] = f2bf(acc[mi][ni][j]);
      }
    }
}

// ---------------- bf16-A 256x256 deep-pipelined GEMM (r4-verified, ~30 us) ------------------
template <int MODE>  // 3: stage+vmcnt(8); 2: vmcnt(4); 1: vmcnt(0); 0: none
__device__ __forceinline__ void subtile_step(u16* shp, int slot, int slot3, int aoff, int boff,
                                             int wv, const u16*& pA0, const u16*& pA1,
                                             const u16*& pB0, const u16*& pB1,
                                             f32x4 (&acc)[8][4]) {
  const u16* Ab = shp + slot * 16384 + aoff;
  const u16* Bb = shp + slot * 16384 + 8192 + boff;
  bf16x8 aF[8], bF[4];
#pragma unroll
  for (int i = 0; i < 4; ++i) aF[i] = *(const bf16x8*)(Ab + i * 512);
#pragma unroll
  for (int i = 0; i < 4; ++i) bF[i] = *(const bf16x8*)(Bb + i * 512);
#pragma unroll
  for (int i = 4; i < 8; ++i) aF[i] = *(const bf16x8*)(Ab + i * 512);
  if (MODE == 3) {
    u16* da = shp + slot3 * 16384 + wv * 1024;
    GLDS16(pA0, da); GLDS16(pA1, da + 512);
    u16* db = shp + slot3 * 16384 + 8192 + wv * 1024;
    GLDS16(pB0, db); GLDS16(pB1, db + 512);
    pA0 += 32; pA1 += 32; pB0 += 32; pB1 += 32;
  }
  __builtin_amdgcn_s_setprio(1);
#pragma unroll
  for (int mf = 0; mf < 8; ++mf)
#pragma unroll
    for (int nf = 0; nf < 4; ++nf)
      acc[mf][nf] = __builtin_amdgcn_mfma_f32_16x16x32_bf16(aF[mf], bF[nf], acc[mf][nf], 0, 0, 0);
  __builtin_amdgcn_s_setprio(0);
  if (MODE == 3) asm volatile("s_waitcnt vmcnt(8)" ::: "memory");
  if (MODE == 2) asm volatile("s_waitcnt vmcnt(4)" ::: "memory");
  if (MODE == 1) asm volatile("s_waitcnt vmcnt(0)" ::: "memory");
  __builtin_amdgcn_s_barrier();
}

template <bool RELU, bool HASBIAS, typename OUT>
__global__ __launch_bounds__(512, 2) void gemm256(const u16* __restrict__ A,
                                                  const u16* __restrict__ W,
                                                  const float* __restrict__ bias,
                                                  OUT* __restrict__ C) {
  extern __shared__ u16 sh[];
  const int t = threadIdx.x;
  const int wv = t >> 6, l = t & 63;
  const int wm = wv >> 2, wn = wv & 3;
  const int l15 = l & 15, lg = l >> 4;

  const int bid = blockIdx.x;
  const int logical = (bid & 7) * 32 + (bid >> 3);
  const int m0 = (logical >> 2) * 256;
  const int n0 = (logical & 3) * 256;

  const int koff = (lg ^ ((l15 >> 1) & 3)) * 8;
  const int aoff = (wm * 128 + l15) * 32 + koff;
  const int boff = (wn * 64 + l15) * 32 + koff;

  const int rowst = wv * 32 + (l >> 2);
  const int ksl = ((l & 3) ^ ((l >> 3) & 3)) * 8;
  const u16* pA0 = A + (size_t)(m0 + rowst) * H_DIM + ksl;
  const u16* pA1 = pA0 + 16 * H_DIM;
  const u16* pB0 = W + (size_t)(n0 + rowst) * H_DIM + ksl;
  const u16* pB1 = pB0 + 16 * H_DIM;

  f32x4 acc[8][4] = {};

#pragma unroll
  for (int s = 0; s < 3; ++s) {
    u16* da = sh + s * 16384 + wv * 1024;
    GLDS16(pA0, da); GLDS16(pA1, da + 512);
    u16* db = sh + s * 16384 + 8192 + wv * 1024;
    GLDS16(pB0, db); GLDS16(pB1, db + 512);
    pA0 += 32; pA1 += 32; pB0 += 32; pB1 += 32;
  }
  asm volatile("s_waitcnt vmcnt(8)" ::: "memory");
  __builtin_amdgcn_s_barrier();

  for (int s = 0; s < 29; ++s)
    subtile_step<3>(sh, s & 3, (s + 3) & 3, aoff, boff, wv, pA0, pA1, pB0, pB1, acc);
  subtile_step<2>(sh, 1, 0, aoff, boff, wv, pA0, pA1, pB0, pB1, acc);
  subtile_step<1>(sh, 2, 0, aoff, boff, wv, pA0, pA1, pB0, pB1, acc);
  subtile_step<0>(sh, 3, 0, aoff, boff, wv, pA0, pA1, pB0, pB1, acc);

  float bv[4];
#pragma unroll
  for (int nf = 0; nf < 4; ++nf)
    bv[nf] = HASBIAS ? bias[n0 + wn * 64 + nf * 16 + l15] : 0.0f;
#pragma unroll
  for (int mf = 0; mf < 8; ++mf) {
#pragma unroll
    for (int nf = 0; nf < 4; ++nf) {
      const int col = n0 + wn * 64 + nf * 16 + l15;
#pragma unroll
      for (int j = 0; j < 4; ++j) {
        const int row = m0 + wm * 128 + mf * 16 + lg * 4 + j;
        float v = acc[mf][nf][j] + bv[nf];
        if (RELU) v = fmaxf(v, 0.0f);
        if constexpr (sizeof(OUT) == 2)
          C[(size_t)row * H_DIM + col] = (OUT)f2bf(v);
        else
          C[(size_t)row * H_DIM + col] = v;
      }
    }
  }
}

// ---------------- fused liquid-neuron update + LayerNorm (all-bf16 reads, r6-verified) ------
__global__ __launch_bounds__(256) void liquid_ln(const u16* __restrict__ hb,
                                                 const u16* __restrict__ pa,
                                                 const u16* __restrict__ ev,
                                                 const float* __restrict__ bias,
                                                 const float* __restrict__ rtau,
                                                 const float* __restrict__ decay,
                                                 const float* __restrict__ lnw,
                                                 const float* __restrict__ lnb,
                                                 float* __restrict__ out) {
  const int wv = threadIdx.x >> 6, l = threadIdx.x & 63;
  const int row = blockIdx.x * 4 + wv;
  const size_t rb = (size_t)row * H_DIM;

  float d[16];
  float s = 0.f, ss = 0.f;
#pragma unroll
  for (int c = 0; c < 2; ++c) {
    const int col = c * 512 + l * 8;
    float b8[8], r8[8], dc8[8];
    *(float4*)b8 = *(const float4*)(bias + col);
    *(float4*)(b8 + 4) = *(const float4*)(bias + col + 4);
    *(float4*)r8 = *(const float4*)(rtau + col);
    *(float4*)(r8 + 4) = *(const float4*)(rtau + col + 4);
    *(float4*)dc8 = *(const float4*)(decay + col);
    *(float4*)(dc8 + 4) = *(const float4*)(decay + col + 4);
    ushort8 hv = *(const ushort8*)(hb + rb + col);
    ushort8 pv = *(const ushort8*)(pa + rb + col);
    ushort8 evv = *(const ushort8*)(ev + rb + col);
#pragma unroll
    for (int j = 0; j < 8; ++j) {
      const float hf = bf2f(hv[j]);
      const float p = bf2f(pv[j]);
      const float e = bf2f(evv[j]);
      const float num = fmaf(-dc8[j], hf, fmaf(1.0f + p, e, b8[j]));
      const float val = num * (1.0f + __expf(-p)) * r8[j];
      d[c * 8 + j] = val;
      s += val;
      ss += val * val;
    }
  }
#pragma unroll
  for (int off = 32; off; off >>= 1) {
    s += __shfl_xor(s, off);
    ss += __shfl_xor(ss, off);
  }
  const float mu = s * (1.0f / H_DIM);
  const float var = ss * (1.0f / H_DIM) - mu * mu;
  const float rstd = rsqrtf(var + 1e-5f);

#pragma unroll
  for (int c = 0; c < 2; ++c) {
    const int col = c * 512 + l * 8;
    float w8[8], lb8[8], o[8];
    *(float4*)w8 = *(const float4*)(lnw + col);
    *(float4*)(w8 + 4) = *(const float4*)(lnw + col + 4);
    *(float4*)lb8 = *(const float4*)(lnb + col);
    *(float4*)(lb8 + 4) = *(const float4*)(lnb + col + 4);
#pragma unroll
    for (int j = 0; j < 8; ++j) o[j] = fmaf((d[c * 8 + j] - mu) * rstd, w8[j], lb8[j]);
    *(float4*)(out + rb + col) = *(float4*)o;
    *(float4*)(out + rb + col + 4) = *(float4*)(o + 4);
  }
}

extern "C" void kernel_launch(void* const* d_in, const int* in_sizes, int n_in,
                              void* d_out, int out_size, void* d_ws, size_t ws_size,
                              hipStream_t stream) {
  // setup_inputs order: t, h, e, W_rec, bias, tau, decay, ln_w, ln_b,
  //                     ce_w1, ce_b1, ce_w2, ce_b2, pm_w, pm_b
  const float* h = (const float*)d_in[1];
  const float* e = (const float*)d_in[2];
  const float* Wrec = (const float*)d_in[3];
  const float* bias = (const float*)d_in[4];
  const float* tau = (const float*)d_in[5];
  const float* decay = (const float*)d_in[6];
  const float* lnw = (const float*)d_in[7];
  const float* lnb = (const float*)d_in[8];
  const float* ce_w1 = (const float*)d_in[9];
  const float* ce_b1 = (const float*)d_in[10];
  const float* ce_w2 = (const float*)d_in[11];
  const float* ce_b2 = (const float*)d_in[12];
  const float* pm_w = (const float*)d_in[13];
  const float* pm_b = (const float*)d_in[14];
  float* out = (float*)d_out;

  char* ws = (char*)d_ws;
  const size_t MB = 1024 * 1024;
  // [0,2) w1b | [2,4) w2t | [4,6) w3b(pm_w) | [6,8) w4b(Wrec) | [8,10) W32b
  // [10,11) rtau @10MB, b32 @10MB+8KB | [12,44) hbf (live to ln) | [44,76) ebf
  // [76,108) t1 -> evb (t1 dead after Gpa) | [108,140) pab.  Peak 140 MB.
  u16* w1b = (u16*)(ws + 0 * MB);
  u16* w2t = (u16*)(ws + 2 * MB);
  u16* w3b = (u16*)(ws + 4 * MB);
  u16* w4b = (u16*)(ws + 6 * MB);
  u16* W32b = (u16*)(ws + 8 * MB);
  float* rtau = (float*)(ws + 10 * MB);
  float* b32 = (float*)(ws + 10 * MB + 8192);
  u16* hbf = (u16*)(ws + 12 * MB);
  u16* ebf = (u16*)(ws + 44 * MB);
  u16* t1 = (u16*)(ws + 76 * MB);
  u16* evb = (u16*)(ws + 76 * MB);  // over t1 (dead after Gpa; stream-serial)
  u16* pab = (u16*)(ws + 108 * MB);

  cvt_all<<<4865, 256, 0, stream>>>(h, e, ce_w1, pm_w, Wrec, hbf, ebf, w1b, w3b, w4b, tau, rtau);
  tr_cvt_w2<<<256, 256, 0, stream>>>(ce_w2, w2t);
  b32_prep<<<4, 256, 0, stream>>>(pm_w, ce_b2, pm_b, b32);
  w32_gemm<<<256, 256, 0, stream>>>(w3b, w2t, W32b);

  const int LDS_BYTES = 131072;
  hipFuncSetAttribute((const void*)gemm256<true, true, u16>,
                      hipFuncAttributeMaxDynamicSharedMemorySize, LDS_BYTES);
  hipFuncSetAttribute((const void*)gemm256<false, true, u16>,
                      hipFuncAttributeMaxDynamicSharedMemorySize, LDS_BYTES);
  hipFuncSetAttribute((const void*)gemm256<false, false, u16>,
                      hipFuncAttributeMaxDynamicSharedMemorySize, LDS_BYTES);

  const int NWG = (B_DIM / 256) * (H_DIM / 256);  // 256 blocks = 1 per CU
  gemm256<true, true, u16><<<NWG, 512, LDS_BYTES, stream>>>(hbf, w1b, ce_b1, t1);
  gemm256<false, true, u16><<<NWG, 512, LDS_BYTES, stream>>>(t1, W32b, b32, pab);
  gemm256<false, false, u16><<<NWG, 512, LDS_BYTES, stream>>>(ebf, w4b, nullptr, evb);

  liquid_ln<<<B_DIM / 4, 256, 0, stream>>>(hbf, pab, evb, bias, rtau, decay, lnw, lnb, out);
}

// Round 11
// 219.730 us; speedup vs baseline: 1.0130x; 1.0119x over previous
//
#include <hip/hip_runtime.h>
#include <stdint.h>

#define H_DIM 1024
#define B_DIM 16384

typedef unsigned short u16;
typedef short bf16x8 __attribute__((ext_vector_type(8)));
typedef unsigned short ushort8 __attribute__((ext_vector_type(8)));
typedef float f32x4 __attribute__((ext_vector_type(4)));

__device__ __forceinline__ u16 f2bf(float f) {
  union { float f; uint32_t u; } v; v.f = f;
  uint32_t r = v.u + 0x7fffu + ((v.u >> 16) & 1u);
  return (u16)(r >> 16);
}
__device__ __forceinline__ float bf2f(u16 x) {
  union { uint32_t u; float f; } v; v.u = ((uint32_t)x) << 16;
  return v.f;
}

#define GLDS16(gsrc, ldst)                                                                 \
  __builtin_amdgcn_global_load_lds((const __attribute__((address_space(1))) void*)(gsrc),  \
                                   (__attribute__((address_space(3))) void*)(ldst), 16, 0, 0)

// ---------------- cvt v2: 16B-coalesced loads AND stores via LDS repack ---------------------
// 2:1 fp32->bf16 can't be 16B/16B lane-contiguous without redistribution (r4: 8B stores ->
// 3.6 TB/s; r7: strided loads -> 3.4). Repack through LDS: 2x float4 load -> cvt -> 2x 8B
// ds_write -> barrier -> 1x ds_read_b128 -> 1x 16B global store. 8KB in / 4KB out per iter.
__device__ __forceinline__ ushort4 cvt4(float4 a) {
  ushort4 o;
  o.x = f2bf(a.x); o.y = f2bf(a.y); o.z = f2bf(a.z); o.w = f2bf(a.w);
  return o;
}

__device__ __forceinline__ void cvt_region2(const float* __restrict__ in, u16* __restrict__ out,
                                            int bidx, int nblocks, int nchunks, char* lds) {
  const int t = threadIdx.x;
  const float4* in4 = (const float4*)in;
  ushort8* out8 = (ushort8*)out;
  for (int ch = bidx; ch < nchunks; ch += nblocks) {
    float4 a = in4[(size_t)ch * 512 + t];
    float4 b = in4[(size_t)ch * 512 + 256 + t];
    ushort4 ca = cvt4(a), cb = cvt4(b);
    __syncthreads();
    *(ushort4*)(lds + t * 8) = ca;
    *(ushort4*)(lds + 2048 + t * 8) = cb;
    __syncthreads();
    ushort8 o = *(const ushort8*)(lds + t * 16);
    out8[(size_t)ch * 256 + t] = o;
  }
}

__global__ __launch_bounds__(256) void cvt_all(const float* __restrict__ h,
                                               const float* __restrict__ e,
                                               const float* __restrict__ w1f,
                                               const float* __restrict__ pmwf,
                                               const float* __restrict__ wrecf,
                                               u16* __restrict__ hb, u16* __restrict__ eb,
                                               u16* __restrict__ o1, u16* __restrict__ o3,
                                               u16* __restrict__ o4,
                                               const float* __restrict__ tau,
                                               float* __restrict__ rtau) {
  __shared__ ushort8 lds8[256];
  char* lds = (char*)lds8;
  const int b = blockIdx.x;
  const int BHC = (B_DIM * H_DIM) / 2048;  // 8192 chunks of 8KB
  const int HHC = (H_DIM * H_DIM) / 2048;  // 512 chunks
  if (b < 2048) {
    cvt_region2(h, hb, b, 2048, BHC, lds);
  } else if (b < 4096) {
    cvt_region2(e, eb, b - 2048, 2048, BHC, lds);
  } else if (b < 4352) {
    cvt_region2(w1f, o1, b - 4096, 256, HHC, lds);
  } else if (b < 4608) {
    cvt_region2(pmwf, o3, b - 4352, 256, HHC, lds);
  } else if (b < 4864) {
    cvt_region2(wrecf, o4, b - 4608, 256, HHC, lds);
  } else {
    for (int i = threadIdx.x; i < H_DIM; i += 256) rtau[i] = 1.0f / tau[i];
  }
}

// ---------------- transpose-cvt of ce_w2 (r7-verified) + b32 merged -------------------------
__global__ __launch_bounds__(256) void tr_cvt_w2_b32(const float* __restrict__ in,
                                                     u16* __restrict__ out,
                                                     const float* __restrict__ pmw,
                                                     const float* __restrict__ ceb2,
                                                     const float* __restrict__ pmb,
                                                     float* __restrict__ b32) {
  const int t = threadIdx.x;
  if (blockIdx.x >= 256) {
    // b32[i] = dot(pm_w[i,:], ce_b2) + pm_b[i]
    const int i = (blockIdx.x - 256) * 256 + t;
    const float4* w4 = (const float4*)(pmw + (size_t)i * H_DIM);
    const float4* b4 = (const float4*)ceb2;
    float acc = pmb[i];
    for (int k = 0; k < 256; ++k) {
      float4 w = w4[k], b = b4[k];
      acc += w.x * b.x + w.y * b.y + w.z * b.z + w.w * b.w;
    }
    b32[i] = acc;
    return;
  }
  __shared__ float tile[64][65];
  const int r0 = (blockIdx.x >> 4) * 64;
  const int c0 = (blockIdx.x & 15) * 64;
  const float4* in4 = (const float4*)in;
#pragma unroll
  for (int it = 0; it < 4; ++it) {
    const int idx = it * 256 + t;
    const int r = idx >> 4, c4 = idx & 15;
    float4 v = in4[(size_t)(r0 + r) * 256 + (c0 >> 2) + c4];
    tile[r][c4 * 4 + 0] = v.x; tile[r][c4 * 4 + 1] = v.y;
    tile[r][c4 * 4 + 2] = v.z; tile[r][c4 * 4 + 3] = v.w;
  }
  __syncthreads();
  ushort4* out4 = (ushort4*)out;
#pragma unroll
  for (int it = 0; it < 4; ++it) {
    const int idx = it * 256 + t;
    const int c = idx >> 4, r4 = idx & 15;
    ushort4 o;
    o.x = f2bf(tile[r4 * 4 + 0][c]); o.y = f2bf(tile[r4 * 4 + 1][c]);
    o.z = f2bf(tile[r4 * 4 + 2][c]); o.w = f2bf(tile[r4 * 4 + 3][c]);
    out4[(size_t)(c0 + c) * 256 + (r0 >> 2) + r4] = o;
  }
}

// ---------------- W32 = pm_w @ ce_w2 (1024^3, r7-verified) ----------------------------------
__global__ __launch_bounds__(256) void w32_gemm(const u16* __restrict__ A,
                                                const u16* __restrict__ Wt,
                                                u16* __restrict__ C) {
  const int t = threadIdx.x;
  const int wv = t >> 6, l = t & 63;
  const int l15 = l & 15, lg = l >> 4;
  const int m0 = (blockIdx.x >> 4) * 64 + (wv >> 1) * 32;
  const int n0 = (blockIdx.x & 15) * 64 + (wv & 1) * 32;

  const u16* ap0 = A + (size_t)(m0 + l15) * H_DIM + lg * 8;
  const u16* ap1 = ap0 + 16 * H_DIM;
  const u16* bp0 = Wt + (size_t)(n0 + l15) * H_DIM + lg * 8;
  const u16* bp1 = bp0 + 16 * H_DIM;

  f32x4 acc[2][2] = {};
#pragma unroll
  for (int kt = 0; kt < 32; ++kt) {
    bf16x8 aF[2], bF[2];
    aF[0] = *(const bf16x8*)(ap0 + kt * 32);
    aF[1] = *(const bf16x8*)(ap1 + kt * 32);
    bF[0] = *(const bf16x8*)(bp0 + kt * 32);
    bF[1] = *(const bf16x8*)(bp1 + kt * 32);
#pragma unroll
    for (int mi = 0; mi < 2; ++mi)
#pragma unroll
      for (int ni = 0; ni < 2; ++ni)
        acc[mi][ni] =
            __builtin_amdgcn_mfma_f32_16x16x32_bf16(aF[mi], bF[ni], acc[mi][ni], 0, 0, 0);
  }
#pragma unroll
  for (int mi = 0; mi < 2; ++mi)
#pragma unroll
    for (int ni = 0; ni < 2; ++ni) {
      const int col = n0 + ni * 16 + l15;
#pragma unroll
      for (int j = 0; j < 4; ++j) {
        const int row = m0 + mi * 16 + lg * 4 + j;
        C[(size_t)row * H_DIM + col] = f2bf(acc[mi][ni][j]);
      }
    }
}

// ---------------- bf16-A 256x256 deep-pipelined GEMM (r4-verified) --------------------------
template <int MODE>  // 3: stage+vmcnt(8); 2: vmcnt(4); 1: vmcnt(0); 0: none
__device__ __forceinline__ void subtile_step(u16* shp, int slot, int slot3, int aoff, int boff,
                                             int wv, const u16*& pA0, const u16*& pA1,
                                             const u16*& pB0, const u16*& pB1,
                                             f32x4 (&acc)[8][4]) {
  const u16* Ab = shp + slot * 16384 + aoff;
  const u16* Bb = shp + slot * 16384 + 8192 + boff;
  bf16x8 aF[8], bF[4];
#pragma unroll
  for (int i = 0; i < 4; ++i) aF[i] = *(const bf16x8*)(Ab + i * 512);
#pragma unroll
  for (int i = 0; i < 4; ++i) bF[i] = *(const bf16x8*)(Bb + i * 512);
#pragma unroll
  for (int i = 4; i < 8; ++i) aF[i] = *(const bf16x8*)(Ab + i * 512);
  if (MODE == 3) {
    u16* da = shp + slot3 * 16384 + wv * 1024;
    GLDS16(pA0, da); GLDS16(pA1, da + 512);
    u16* db = shp + slot3 * 16384 + 8192 + wv * 1024;
    GLDS16(pB0, db); GLDS16(pB1, db + 512);
    pA0 += 32; pA1 += 32; pB0 += 32; pB1 += 32;
  }
  __builtin_amdgcn_s_setprio(1);
#pragma unroll
  for (int mf = 0; mf < 8; ++mf)
#pragma unroll
    for (int nf = 0; nf < 4; ++nf)
      acc[mf][nf] = __builtin_amdgcn_mfma_f32_16x16x32_bf16(aF[mf], bF[nf], acc[mf][nf], 0, 0, 0);
  __builtin_amdgcn_s_setprio(0);
  if (MODE == 3) asm volatile("s_waitcnt vmcnt(8)" ::: "memory");
  if (MODE == 2) asm volatile("s_waitcnt vmcnt(4)" ::: "memory");
  if (MODE == 1) asm volatile("s_waitcnt vmcnt(0)" ::: "memory");
  __builtin_amdgcn_s_barrier();
}

template <bool RELU, bool HASBIAS, typename OUT>
__global__ __launch_bounds__(512, 2) void gemm256(const u16* __restrict__ A,
                                                  const u16* __restrict__ W,
                                                  const float* __restrict__ bias,
                                                  OUT* __restrict__ C) {
  extern __shared__ u16 sh[];
  const int t = threadIdx.x;
  const int wv = t >> 6, l = t & 63;
  const int wm = wv >> 2, wn = wv & 3;
  const int l15 = l & 15, lg = l >> 4;

  const int bid = blockIdx.x;
  const int logical = (bid & 7) * 32 + (bid >> 3);
  const int m0 = (logical >> 2) * 256;
  const int n0 = (logical & 3) * 256;

  const int koff = (lg ^ ((l15 >> 1) & 3)) * 8;
  const int aoff = (wm * 128 + l15) * 32 + koff;
  const int boff = (wn * 64 + l15) * 32 + koff;

  const int rowst = wv * 32 + (l >> 2);
  const int ksl = ((l & 3) ^ ((l >> 3) & 3)) * 8;
  const u16* pA0 = A + (size_t)(m0 + rowst) * H_DIM + ksl;
  const u16* pA1 = pA0 + 16 * H_DIM;
  const u16* pB0 = W + (size_t)(n0 + rowst) * H_DIM + ksl;
  const u16* pB1 = pB0 + 16 * H_DIM;

  f32x4 acc[8][4] = {};

#pragma unroll
  for (int s = 0; s < 3; ++s) {
    u16* da = sh + s * 16384 + wv * 1024;
    GLDS16(pA0, da); GLDS16(pA1, da + 512);
    u16* db = sh + s * 16384 + 8192 + wv * 1024;
    GLDS16(pB0, db); GLDS16(pB1, db + 512);
    pA0 += 32; pA1 += 32; pB0 += 32; pB1 += 32;
  }
  asm volatile("s_waitcnt vmcnt(8)" ::: "memory");
  __builtin_amdgcn_s_barrier();

  for (int s = 0; s < 29; ++s)
    subtile_step<3>(sh, s & 3, (s + 3) & 3, aoff, boff, wv, pA0, pA1, pB0, pB1, acc);
  subtile_step<2>(sh, 1, 0, aoff, boff, wv, pA0, pA1, pB0, pB1, acc);
  subtile_step<1>(sh, 2, 0, aoff, boff, wv, pA0, pA1, pB0, pB1, acc);
  subtile_step<0>(sh, 3, 0, aoff, boff, wv, pA0, pA1, pB0, pB1, acc);

  float bv[4];
#pragma unroll
  for (int nf = 0; nf < 4; ++nf)
    bv[nf] = HASBIAS ? bias[n0 + wn * 64 + nf * 16 + l15] : 0.0f;
#pragma unroll
  for (int mf = 0; mf < 8; ++mf) {
#pragma unroll
    for (int nf = 0; nf < 4; ++nf) {
      const int col = n0 + wn * 64 + nf * 16 + l15;
#pragma unroll
      for (int j = 0; j < 4; ++j) {
        const int row = m0 + wm * 128 + mf * 16 + lg * 4 + j;
        float v = acc[mf][nf][j] + bv[nf];
        if (RELU) v = fmaxf(v, 0.0f);
        if constexpr (sizeof(OUT) == 2)
          C[(size_t)row * H_DIM + col] = (OUT)f2bf(v);
        else
          C[(size_t)row * H_DIM + col] = v;
      }
    }
  }
}

// ---------------- fused liquid-neuron update + LayerNorm (all-bf16 reads, r6-verified) ------
__global__ __launch_bounds__(256) void liquid_ln(const u16* __restrict__ hb,
                                                 const u16* __restrict__ pa,
                                                 const u16* __restrict__ ev,
                                                 const float* __restrict__ bias,
                                                 const float* __restrict__ rtau,
                                                 const float* __restrict__ decay,
                                                 const float* __restrict__ lnw,
                                                 const float* __restrict__ lnb,
                                                 float* __restrict__ out) {
  const int wv = threadIdx.x >> 6, l = threadIdx.x & 63;
  const int row = blockIdx.x * 4 + wv;
  const size_t rb = (size_t)row * H_DIM;

  float d[16];
  float s = 0.f, ss = 0.f;
#pragma unroll
  for (int c = 0; c < 2; ++c) {
    const int col = c * 512 + l * 8;
    float b8[8], r8[8], dc8[8];
    *(float4*)b8 = *(const float4*)(bias + col);
    *(float4*)(b8 + 4) = *(const float4*)(bias + col + 4);
    *(float4*)r8 = *(const float4*)(rtau + col);
    *(float4*)(r8 + 4) = *(const float4*)(rtau + col + 4);
    *(float4*)dc8 = *(const float4*)(decay + col);
    *(float4*)(dc8 + 4) = *(const float4*)(decay + col + 4);
    ushort8 hv = *(const ushort8*)(hb + rb + col);
    ushort8 pv = *(const ushort8*)(pa + rb + col);
    ushort8 evv = *(const ushort8*)(ev + rb + col);
#pragma unroll
    for (int j = 0; j < 8; ++j) {
      const float hf = bf2f(hv[j]);
      const float p = bf2f(pv[j]);
      const float e = bf2f(evv[j]);
      const float num = fmaf(-dc8[j], hf, fmaf(1.0f + p, e, b8[j]));
      const float val = num * (1.0f + __expf(-p)) * r8[j];
      d[c * 8 + j] = val;
      s += val;
      ss += val * val;
    }
  }
#pragma unroll
  for (int off = 32; off; off >>= 1) {
    s += __shfl_xor(s, off);
    ss += __shfl_xor(ss, off);
  }
  const float mu = s * (1.0f / H_DIM);
  const float var = ss * (1.0f / H_DIM) - mu * mu;
  const float rstd = rsqrtf(var + 1e-5f);

#pragma unroll
  for (int c = 0; c < 2; ++c) {
    const int col = c * 512 + l * 8;
    float w8[8], lb8[8], o[8];
    *(float4*)w8 = *(const float4*)(lnw + col);
    *(float4*)(w8 + 4) = *(const float4*)(lnw + col + 4);
    *(float4*)lb8 = *(const float4*)(lnb + col);
    *(float4*)(lb8 + 4) = *(const float4*)(lnb + col + 4);
#pragma unroll
    for (int j = 0; j < 8; ++j) o[j] = fmaf((d[c * 8 + j] - mu) * rstd, w8[j], lb8[j]);
    *(float4*)(out + rb + col) = *(float4*)o;
    *(float4*)(out + rb + col + 4) = *(float4*)(o + 4);
  }
}

extern "C" void kernel_launch(void* const* d_in, const int* in_sizes, int n_in,
                              void* d_out, int out_size, void* d_ws, size_t ws_size,
                              hipStream_t stream) {
  // setup_inputs order: t, h, e, W_rec, bias, tau, decay, ln_w, ln_b,
  //                     ce_w1, ce_b1, ce_w2, ce_b2, pm_w, pm_b
  const float* h = (const float*)d_in[1];
  const float* e = (const float*)d_in[2];
  const float* Wrec = (const float*)d_in[3];
  const float* bias = (const float*)d_in[4];
  const float* tau = (const float*)d_in[5];
  const float* decay = (const float*)d_in[6];
  const float* lnw = (const float*)d_in[7];
  const float* lnb = (const float*)d_in[8];
  const float* ce_w1 = (const float*)d_in[9];
  const float* ce_b1 = (const float*)d_in[10];
  const float* ce_w2 = (const float*)d_in[11];
  const float* ce_b2 = (const float*)d_in[12];
  const float* pm_w = (const float*)d_in[13];
  const float* pm_b = (const float*)d_in[14];
  float* out = (float*)d_out;

  char* ws = (char*)d_ws;
  const size_t MB = 1024 * 1024;
  // [0,2) w1b | [2,4) w2t | [4,6) w3b(pm_w) | [6,8) w4b(Wrec) | [8,10) W32b
  // [10,11) rtau @10MB, b32 @10MB+8KB | [12,44) hbf (live to ln) | [44,76) ebf
  // [76,108) t1 -> evb (t1 dead after Gpa) | [108,140) pab.  Peak 140 MB.
  u16* w1b = (u16*)(ws + 0 * MB);
  u16* w2t = (u16*)(ws + 2 * MB);
  u16* w3b = (u16*)(ws + 4 * MB);
  u16* w4b = (u16*)(ws + 6 * MB);
  u16* W32b = (u16*)(ws + 8 * MB);
  float* rtau = (float*)(ws + 10 * MB);
  float* b32 = (float*)(ws + 10 * MB + 8192);
  u16* hbf = (u16*)(ws + 12 * MB);
  u16* ebf = (u16*)(ws + 44 * MB);
  u16* t1 = (u16*)(ws + 76 * MB);
  u16* evb = (u16*)(ws + 76 * MB);  // over t1 (dead after Gpa; stream-serial)
  u16* pab = (u16*)(ws + 108 * MB);

  cvt_all<<<4865, 256, 0, stream>>>(h, e, ce_w1, pm_w, Wrec, hbf, ebf, w1b, w3b, w4b, tau, rtau);
  tr_cvt_w2_b32<<<260, 256, 0, stream>>>(ce_w2, w2t, pm_w, ce_b2, pm_b, b32);
  w32_gemm<<<256, 256, 0, stream>>>(w3b, w2t, W32b);

  const int LDS_BYTES = 131072;
  hipFuncSetAttribute((const void*)gemm256<true, true, u16>,
                      hipFuncAttributeMaxDynamicSharedMemorySize, LDS_BYTES);
  hipFuncSetAttribute((const void*)gemm256<false, true, u16>,
                      hipFuncAttributeMaxDynamicSharedMemorySize, LDS_BYTES);
  hipFuncSetAttribute((const void*)gemm256<false, false, u16>,
                      hipFuncAttributeMaxDynamicSharedMemorySize, LDS_BYTES);

  const int NWG = (B_DIM / 256) * (H_DIM / 256);  // 256 blocks = 1 per CU
  gemm256<true, true, u16><<<NWG, 512, LDS_BYTES, stream>>>(hbf, w1b, ce_b1, t1);
  gemm256<false, true, u16><<<NWG, 512, LDS_BYTES, stream>>>(t1, W32b, b32, pab);
  gemm256<false, false, u16><<<NWG, 512, LDS_BYTES, stream>>>(ebf, w4b, nullptr, evb);

  liquid_ln<<<B_DIM / 4, 256, 0, stream>>>(hbf, pab, evb, bias, rtau, decay, lnw, lnb, out);
}

// Round 12
// 218.919 us; speedup vs baseline: 1.0168x; 1.0037x over previous
//
#include <hip/hip_runtime.h>
#include <stdint.h>

#define H_DIM 1024
#define B_DIM 16384

typedef unsigned short u16;
typedef short bf16x8 __attribute__((ext_vector_type(8)));
typedef unsigned short ushort8 __attribute__((ext_vector_type(8)));
typedef float f32x4 __attribute__((ext_vector_type(4)));

__device__ __forceinline__ u16 f2bf(float f) {
  union { float f; uint32_t u; } v; v.f = f;
  uint32_t r = v.u + 0x7fffu + ((v.u >> 16) & 1u);
  return (u16)(r >> 16);
}
__device__ __forceinline__ float bf2f(u16 x) {
  union { uint32_t u; float f; } v; v.u = ((uint32_t)x) << 16;
  return v.f;
}
__device__ __forceinline__ ushort4 cvt4(float4 a) {
  ushort4 o;
  o.x = f2bf(a.x); o.y = f2bf(a.y); o.z = f2bf(a.z); o.w = f2bf(a.w);
  return o;
}

#define GLDS16(gsrc, ldst)                                                                 \
  __builtin_amdgcn_global_load_lds((const __attribute__((address_space(1))) void*)(gsrc),  \
                                   (__attribute__((address_space(3))) void*)(ldst), 16, 0, 0)

// ---------------- cvt v3: ONE-SHOT, ILP-8 ---------------------------------------------------
// r4/r10/r11 all latency-bound (VALU 4.6%, HBM 15%, nothing saturated) with <=2 loads in
// flight per thread. liquid_ln (9 loads in flight, one-shot) hits ~6.7 TB/s effective.
// Here: block = one 32KB chunk; thread issues 8 independent coalesced float4 loads
// (4KB-apart segments, DRAM-local), then 8 independent ushort4 stores. No loop, no LDS.
__global__ __launch_bounds__(256) void cvt_all(const float* __restrict__ h,
                                               const float* __restrict__ e,
                                               const float* __restrict__ w1f,
                                               const float* __restrict__ pmwf,
                                               const float* __restrict__ wrecf,
                                               u16* __restrict__ hb, u16* __restrict__ eb,
                                               u16* __restrict__ o1, u16* __restrict__ o3,
                                               u16* __restrict__ o4,
                                               const float* __restrict__ tau,
                                               float* __restrict__ rtau) {
  const int b = blockIdx.x;
  const int t = threadIdx.x;
  const float* in;
  u16* out;
  int chunk;
  if (b < 2048) {
    in = h; out = hb; chunk = b;
  } else if (b < 4096) {
    in = e; out = eb; chunk = b - 2048;
  } else if (b < 4224) {
    in = w1f; out = o1; chunk = b - 4096;
  } else if (b < 4352) {
    in = pmwf; out = o3; chunk = b - 4224;
  } else if (b < 4480) {
    in = wrecf; out = o4; chunk = b - 4352;
  } else {
    for (int i = t; i < H_DIM; i += 256) rtau[i] = 1.0f / tau[i];
    return;
  }
  const float4* in4 = (const float4*)in + (size_t)chunk * 2048 + t;
  ushort4* out4 = (ushort4*)out + (size_t)chunk * 2048 + t;
  float4 v[8];
#pragma unroll
  for (int k = 0; k < 8; ++k) v[k] = in4[k * 256];
#pragma unroll
  for (int k = 0; k < 8; ++k) out4[k * 256] = cvt4(v[k]);
}

// ---------------- transpose-cvt of ce_w2 (r7-verified) + b32 merged -------------------------
__global__ __launch_bounds__(256) void tr_cvt_w2_b32(const float* __restrict__ in,
                                                     u16* __restrict__ out,
                                                     const float* __restrict__ pmw,
                                                     const float* __restrict__ ceb2,
                                                     const float* __restrict__ pmb,
                                                     float* __restrict__ b32) {
  const int t = threadIdx.x;
  if (blockIdx.x >= 256) {
    const int i = (blockIdx.x - 256) * 256 + t;
    const float4* w4 = (const float4*)(pmw + (size_t)i * H_DIM);
    const float4* b4 = (const float4*)ceb2;
    float acc = pmb[i];
    for (int k = 0; k < 256; ++k) {
      float4 w = w4[k], b = b4[k];
      acc += w.x * b.x + w.y * b.y + w.z * b.z + w.w * b.w;
    }
    b32[i] = acc;
    return;
  }
  __shared__ float tile[64][65];
  const int r0 = (blockIdx.x >> 4) * 64;
  const int c0 = (blockIdx.x & 15) * 64;
  const float4* in4 = (const float4*)in;
#pragma unroll
  for (int it = 0; it < 4; ++it) {
    const int idx = it * 256 + t;
    const int r = idx >> 4, c4 = idx & 15;
    float4 v = in4[(size_t)(r0 + r) * 256 + (c0 >> 2) + c4];
    tile[r][c4 * 4 + 0] = v.x; tile[r][c4 * 4 + 1] = v.y;
    tile[r][c4 * 4 + 2] = v.z; tile[r][c4 * 4 + 3] = v.w;
  }
  __syncthreads();
  ushort4* out4 = (ushort4*)out;
#pragma unroll
  for (int it = 0; it < 4; ++it) {
    const int idx = it * 256 + t;
    const int c = idx >> 4, r4 = idx & 15;
    ushort4 o;
    o.x = f2bf(tile[r4 * 4 + 0][c]); o.y = f2bf(tile[r4 * 4 + 1][c]);
    o.z = f2bf(tile[r4 * 4 + 2][c]); o.w = f2bf(tile[r4 * 4 + 3][c]);
    out4[(size_t)(c0 + c) * 256 + (r0 >> 2) + r4] = o;
  }
}

// ---------------- W32 = pm_w @ ce_w2 (1024^3, r7-verified) ----------------------------------
__global__ __launch_bounds__(256) void w32_gemm(const u16* __restrict__ A,
                                                const u16* __restrict__ Wt,
                                                u16* __restrict__ C) {
  const int t = threadIdx.x;
  const int wv = t >> 6, l = t & 63;
  const int l15 = l & 15, lg = l >> 4;
  const int m0 = (blockIdx.x >> 4) * 64 + (wv >> 1) * 32;
  const int n0 = (blockIdx.x & 15) * 64 + (wv & 1) * 32;

  const u16* ap0 = A + (size_t)(m0 + l15) * H_DIM + lg * 8;
  const u16* ap1 = ap0 + 16 * H_DIM;
  const u16* bp0 = Wt + (size_t)(n0 + l15) * H_DIM + lg * 8;
  const u16* bp1 = bp0 + 16 * H_DIM;

  f32x4 acc[2][2] = {};
#pragma unroll
  for (int kt = 0; kt < 32; ++kt) {
    bf16x8 aF[2], bF[2];
    aF[0] = *(const bf16x8*)(ap0 + kt * 32);
    aF[1] = *(const bf16x8*)(ap1 + kt * 32);
    bF[0] = *(const bf16x8*)(bp0 + kt * 32);
    bF[1] = *(const bf16x8*)(bp1 + kt * 32);
#pragma unroll
    for (int mi = 0; mi < 2; ++mi)
#pragma unroll
      for (int ni = 0; ni < 2; ++ni)
        acc[mi][ni] =
            __builtin_amdgcn_mfma_f32_16x16x32_bf16(aF[mi], bF[ni], acc[mi][ni], 0, 0, 0);
  }
#pragma unroll
  for (int mi = 0; mi < 2; ++mi)
#pragma unroll
    for (int ni = 0; ni < 2; ++ni) {
      const int col = n0 + ni * 16 + l15;
#pragma unroll
      for (int j = 0; j < 4; ++j) {
        const int row = m0 + mi * 16 + lg * 4 + j;
        C[(size_t)row * H_DIM + col] = f2bf(acc[mi][ni][j]);
      }
    }
}

// ---------------- bf16-A 256x256 deep-pipelined GEMM (r4-verified) --------------------------
template <int MODE>  // 3: stage+vmcnt(8); 2: vmcnt(4); 1: vmcnt(0); 0: none
__device__ __forceinline__ void subtile_step(u16* shp, int slot, int slot3, int aoff, int boff,
                                             int wv, const u16*& pA0, const u16*& pA1,
                                             const u16*& pB0, const u16*& pB1,
                                             f32x4 (&acc)[8][4]) {
  const u16* Ab = shp + slot * 16384 + aoff;
  const u16* Bb = shp + slot * 16384 + 8192 + boff;
  bf16x8 aF[8], bF[4];
#pragma unroll
  for (int i = 0; i < 4; ++i) aF[i] = *(const bf16x8*)(Ab + i * 512);
#pragma unroll
  for (int i = 0; i < 4; ++i) bF[i] = *(const bf16x8*)(Bb + i * 512);
#pragma unroll
  for (int i = 4; i < 8; ++i) aF[i] = *(const bf16x8*)(Ab + i * 512);
  if (MODE == 3) {
    u16* da = shp + slot3 * 16384 + wv * 1024;
    GLDS16(pA0, da); GLDS16(pA1, da + 512);
    u16* db = shp + slot3 * 16384 + 8192 + wv * 1024;
    GLDS16(pB0, db); GLDS16(pB1, db + 512);
    pA0 += 32; pA1 += 32; pB0 += 32; pB1 += 32;
  }
  __builtin_amdgcn_s_setprio(1);
#pragma unroll
  for (int mf = 0; mf < 8; ++mf)
#pragma unroll
    for (int nf = 0; nf < 4; ++nf)
      acc[mf][nf] = __builtin_amdgcn_mfma_f32_16x16x32_bf16(aF[mf], bF[nf], acc[mf][nf], 0, 0, 0);
  __builtin_amdgcn_s_setprio(0);
  if (MODE == 3) asm volatile("s_waitcnt vmcnt(8)" ::: "memory");
  if (MODE == 2) asm volatile("s_waitcnt vmcnt(4)" ::: "memory");
  if (MODE == 1) asm volatile("s_waitcnt vmcnt(0)" ::: "memory");
  __builtin_amdgcn_s_barrier();
}

template <bool RELU, bool HASBIAS, typename OUT>
__global__ __launch_bounds__(512, 2) void gemm256(const u16* __restrict__ A,
                                                  const u16* __restrict__ W,
                                                  const float* __restrict__ bias,
                                                  OUT* __restrict__ C) {
  extern __shared__ u16 sh[];
  const int t = threadIdx.x;
  const int wv = t >> 6, l = t & 63;
  const int wm = wv >> 2, wn = wv & 3;
  const int l15 = l & 15, lg = l >> 4;

  const int bid = blockIdx.x;
  const int logical = (bid & 7) * 32 + (bid >> 3);
  const int m0 = (logical >> 2) * 256;
  const int n0 = (logical & 3) * 256;

  const int koff = (lg ^ ((l15 >> 1) & 3)) * 8;
  const int aoff = (wm * 128 + l15) * 32 + koff;
  const int boff = (wn * 64 + l15) * 32 + koff;

  const int rowst = wv * 32 + (l >> 2);
  const int ksl = ((l & 3) ^ ((l >> 3) & 3)) * 8;
  const u16* pA0 = A + (size_t)(m0 + rowst) * H_DIM + ksl;
  const u16* pA1 = pA0 + 16 * H_DIM;
  const u16* pB0 = W + (size_t)(n0 + rowst) * H_DIM + ksl;
  const u16* pB1 = pB0 + 16 * H_DIM;

  f32x4 acc[8][4] = {};

#pragma unroll
  for (int s = 0; s < 3; ++s) {
    u16* da = sh + s * 16384 + wv * 1024;
    GLDS16(pA0, da); GLDS16(pA1, da + 512);
    u16* db = sh + s * 16384 + 8192 + wv * 1024;
    GLDS16(pB0, db); GLDS16(pB1, db + 512);
    pA0 += 32; pA1 += 32; pB0 += 32; pB1 += 32;
  }
  asm volatile("s_waitcnt vmcnt(8)" ::: "memory");
  __builtin_amdgcn_s_barrier();

  for (int s = 0; s < 29; ++s)
    subtile_step<3>(sh, s & 3, (s + 3) & 3, aoff, boff, wv, pA0, pA1, pB0, pB1, acc);
  subtile_step<2>(sh, 1, 0, aoff, boff, wv, pA0, pA1, pB0, pB1, acc);
  subtile_step<1>(sh, 2, 0, aoff, boff, wv, pA0, pA1, pB0, pB1, acc);
  subtile_step<0>(sh, 3, 0, aoff, boff, wv, pA0, pA1, pB0, pB1, acc);

  float bv[4];
#pragma unroll
  for (int nf = 0; nf < 4; ++nf)
    bv[nf] = HASBIAS ? bias[n0 + wn * 64 + nf * 16 + l15] : 0.0f;
#pragma unroll
  for (int mf = 0; mf < 8; ++mf) {
#pragma unroll
    for (int nf = 0; nf < 4; ++nf) {
      const int col = n0 + wn * 64 + nf * 16 + l15;
#pragma unroll
      for (int j = 0; j < 4; ++j) {
        const int row = m0 + wm * 128 + mf * 16 + lg * 4 + j;
        float v = acc[mf][nf][j] + bv[nf];
        if (RELU) v = fmaxf(v, 0.0f);
        if constexpr (sizeof(OUT) == 2)
          C[(size_t)row * H_DIM + col] = (OUT)f2bf(v);
        else
          C[(size_t)row * H_DIM + col] = v;
      }
    }
  }
}

// ---------------- fused liquid-neuron update + LayerNorm (all-bf16 reads, r6-verified) ------
__global__ __launch_bounds__(256) void liquid_ln(const u16* __restrict__ hb,
                                                 const u16* __restrict__ pa,
                                                 const u16* __restrict__ ev,
                                                 const float* __restrict__ bias,
                                                 const float* __restrict__ rtau,
                                                 const float* __restrict__ decay,
                                                 const float* __restrict__ lnw,
                                                 const float* __restrict__ lnb,
                                                 float* __restrict__ out) {
  const int wv = threadIdx.x >> 6, l = threadIdx.x & 63;
  const int row = blockIdx.x * 4 + wv;
  const size_t rb = (size_t)row * H_DIM;

  float d[16];
  float s = 0.f, ss = 0.f;
#pragma unroll
  for (int c = 0; c < 2; ++c) {
    const int col = c * 512 + l * 8;
    float b8[8], r8[8], dc8[8];
    *(float4*)b8 = *(const float4*)(bias + col);
    *(float4*)(b8 + 4) = *(const float4*)(bias + col + 4);
    *(float4*)r8 = *(const float4*)(rtau + col);
    *(float4*)(r8 + 4) = *(const float4*)(rtau + col + 4);
    *(float4*)dc8 = *(const float4*)(decay + col);
    *(float4*)(dc8 + 4) = *(const float4*)(decay + col + 4);
    ushort8 hv = *(const ushort8*)(hb + rb + col);
    ushort8 pv = *(const ushort8*)(pa + rb + col);
    ushort8 evv = *(const ushort8*)(ev + rb + col);
#pragma unroll
    for (int j = 0; j < 8; ++j) {
      const float hf = bf2f(hv[j]);
      const float p = bf2f(pv[j]);
      const float e = bf2f(evv[j]);
      const float num = fmaf(-dc8[j], hf, fmaf(1.0f + p, e, b8[j]));
      const float val = num * (1.0f + __expf(-p)) * r8[j];
      d[c * 8 + j] = val;
      s += val;
      ss += val * val;
    }
  }
#pragma unroll
  for (int off = 32; off; off >>= 1) {
    s += __shfl_xor(s, off);
    ss += __shfl_xor(ss, off);
  }
  const float mu = s * (1.0f / H_DIM);
  const float var = ss * (1.0f / H_DIM) - mu * mu;
  const float rstd = rsqrtf(var + 1e-5f);

#pragma unroll
  for (int c = 0; c < 2; ++c) {
    const int col = c * 512 + l * 8;
    float w8[8], lb8[8], o[8];
    *(float4*)w8 = *(const float4*)(lnw + col);
    *(float4*)(w8 + 4) = *(const float4*)(lnw + col + 4);
    *(float4*)lb8 = *(const float4*)(lnb + col);
    *(float4*)(lb8 + 4) = *(const float4*)(lnb + col + 4);
#pragma unroll
    for (int j = 0; j < 8; ++j) o[j] = fmaf((d[c * 8 + j] - mu) * rstd, w8[j], lb8[j]);
    *(float4*)(out + rb + col) = *(float4*)o;
    *(float4*)(out + rb + col + 4) = *(float4*)(o + 4);
  }
}

extern "C" void kernel_launch(void* const* d_in, const int* in_sizes, int n_in,
                              void* d_out, int out_size, void* d_ws, size_t ws_size,
                              hipStream_t stream) {
  // setup_inputs order: t, h, e, W_rec, bias, tau, decay, ln_w, ln_b,
  //                     ce_w1, ce_b1, ce_w2, ce_b2, pm_w, pm_b
  const float* h = (const float*)d_in[1];
  const float* e = (const float*)d_in[2];
  const float* Wrec = (const float*)d_in[3];
  const float* bias = (const float*)d_in[4];
  const float* tau = (const float*)d_in[5];
  const float* decay = (const float*)d_in[6];
  const float* lnw = (const float*)d_in[7];
  const float* lnb = (const float*)d_in[8];
  const float* ce_w1 = (const float*)d_in[9];
  const float* ce_b1 = (const float*)d_in[10];
  const float* ce_w2 = (const float*)d_in[11];
  const float* ce_b2 = (const float*)d_in[12];
  const float* pm_w = (const float*)d_in[13];
  const float* pm_b = (const float*)d_in[14];
  float* out = (float*)d_out;

  char* ws = (char*)d_ws;
  const size_t MB = 1024 * 1024;
  // [0,2) w1b | [2,4) w2t | [4,6) w3b(pm_w) | [6,8) w4b(Wrec) | [8,10) W32b
  // [10,11) rtau @10MB, b32 @10MB+8KB | [12,44) hbf (live to ln) | [44,76) ebf
  // [76,108) t1 -> evb (t1 dead after Gpa) | [108,140) pab.  Peak 140 MB.
  u16* w1b = (u16*)(ws + 0 * MB);
  u16* w2t = (u16*)(ws + 2 * MB);
  u16* w3b = (u16*)(ws + 4 * MB);
  u16* w4b = (u16*)(ws + 6 * MB);
  u16* W32b = (u16*)(ws + 8 * MB);
  float* rtau = (float*)(ws + 10 * MB);
  float* b32 = (float*)(ws + 10 * MB + 8192);
  u16* hbf = (u16*)(ws + 12 * MB);
  u16* ebf = (u16*)(ws + 44 * MB);
  u16* t1 = (u16*)(ws + 76 * MB);
  u16* evb = (u16*)(ws + 76 * MB);  // over t1 (dead after Gpa; stream-serial)
  u16* pab = (u16*)(ws + 108 * MB);

  cvt_all<<<4481, 256, 0, stream>>>(h, e, ce_w1, pm_w, Wrec, hbf, ebf, w1b, w3b, w4b, tau, rtau);
  tr_cvt_w2_b32<<<260, 256, 0, stream>>>(ce_w2, w2t, pm_w, ce_b2, pm_b, b32);
  w32_gemm<<<256, 256, 0, stream>>>(w3b, w2t, W32b);

  const int LDS_BYTES = 131072;
  hipFuncSetAttribute((const void*)gemm256<true, true, u16>,
                      hipFuncAttributeMaxDynamicSharedMemorySize, LDS_BYTES);
  hipFuncSetAttribute((const void*)gemm256<false, true, u16>,
                      hipFuncAttributeMaxDynamicSharedMemorySize, LDS_BYTES);
  hipFuncSetAttribute((const void*)gemm256<false, false, u16>,
                      hipFuncAttributeMaxDynamicSharedMemorySize, LDS_BYTES);

  const int NWG = (B_DIM / 256) * (H_DIM / 256);  // 256 blocks = 1 per CU
  gemm256<true, true, u16><<<NWG, 512, LDS_BYTES, stream>>>(hbf, w1b, ce_b1, t1);
  gemm256<false, true, u16><<<NWG, 512, LDS_BYTES, stream>>>(t1, W32b, b32, pab);
  gemm256<false, false, u16><<<NWG, 512, LDS_BYTES, stream>>>(ebf, w4b, nullptr, evb);

  liquid_ln<<<B_DIM / 4, 256, 0, stream>>>(hbf, pab, evb, bias, rtau, decay, lnw, lnb, out);
}

// Round 13
// 215.144 us; speedup vs baseline: 1.0346x; 1.0175x over previous
//
#include <hip/hip_runtime.h>
#include <stdint.h>

#define H_DIM 1024
#define B_DIM 16384

typedef unsigned short u16;
typedef short bf16x8 __attribute__((ext_vector_type(8)));
typedef unsigned short ushort8 __attribute__((ext_vector_type(8)));
typedef float f32x4 __attribute__((ext_vector_type(4)));

__device__ __forceinline__ u16 f2bf(float f) {
  union { float f; uint32_t u; } v; v.f = f;
  uint32_t r = v.u + 0x7fffu + ((v.u >> 16) & 1u);
  return (u16)(r >> 16);
}
__device__ __forceinline__ float bf2f(u16 x) {
  union { uint32_t u; float f; } v; v.u = ((uint32_t)x) << 16;
  return v.f;
}
__device__ __forceinline__ ushort4 cvt4(float4 a) {
  ushort4 o;
  o.x = f2bf(a.x); o.y = f2bf(a.y); o.z = f2bf(a.z); o.w = f2bf(a.w);
  return o;
}

#define GLDS16(gsrc, ldst)                                                                 \
  __builtin_amdgcn_global_load_lds((const __attribute__((address_space(1))) void*)(gsrc),  \
                                   (__attribute__((address_space(3))) void*)(ldst), 16, 0, 0)

// ---------------- cvt v4: pairwise loads -> 16B stores, one-shot; tr_cvt+b32+rtau merged ----
// Last untested cvt cell: both-sides-16B-stores WITHOUT the LDS hop (r11) or loop.
// Thread handles 4 ushort8 outputs: out8[i] <- cvt(in4[2i], in4[2i+1]).
__global__ __launch_bounds__(256) void cvt_all(const float* __restrict__ h,
                                               const float* __restrict__ e,
                                               const float* __restrict__ w1f,
                                               const float* __restrict__ pmwf,
                                               const float* __restrict__ wrecf,
                                               u16* __restrict__ hb, u16* __restrict__ eb,
                                               u16* __restrict__ o1, u16* __restrict__ o3,
                                               u16* __restrict__ o4,
                                               const float* __restrict__ tau,
                                               float* __restrict__ rtau,
                                               const float* __restrict__ w2f,
                                               u16* __restrict__ w2t,
                                               const float* __restrict__ ceb2,
                                               const float* __restrict__ pmb,
                                               float* __restrict__ b32) {
  __shared__ float tile[64][65];
  const int b = blockIdx.x;
  const int t = threadIdx.x;

  if (b >= 4480) {
    if (b < 4736) {
      // transpose-cvt of ce_w2 (r7-verified)
      const int bb = b - 4480;
      const int r0 = (bb >> 4) * 64;
      const int c0 = (bb & 15) * 64;
      const float4* in4 = (const float4*)w2f;
#pragma unroll
      for (int it = 0; it < 4; ++it) {
        const int idx = it * 256 + t;
        const int r = idx >> 4, c4 = idx & 15;
        float4 v = in4[(size_t)(r0 + r) * 256 + (c0 >> 2) + c4];
        tile[r][c4 * 4 + 0] = v.x; tile[r][c4 * 4 + 1] = v.y;
        tile[r][c4 * 4 + 2] = v.z; tile[r][c4 * 4 + 3] = v.w;
      }
      __syncthreads();
      ushort4* out4 = (ushort4*)w2t;
#pragma unroll
      for (int it = 0; it < 4; ++it) {
        const int idx = it * 256 + t;
        const int c = idx >> 4, r4 = idx & 15;
        ushort4 o;
        o.x = f2bf(tile[r4 * 4 + 0][c]); o.y = f2bf(tile[r4 * 4 + 1][c]);
        o.z = f2bf(tile[r4 * 4 + 2][c]); o.w = f2bf(tile[r4 * 4 + 3][c]);
        out4[(size_t)(c0 + c) * 256 + (r0 >> 2) + r4] = o;
      }
    } else if (b < 4740) {
      // b32[i] = dot(pm_w[i,:], ce_b2) + pm_b[i]
      const int i = (b - 4736) * 256 + t;
      const float4* w4 = (const float4*)(pmwf + (size_t)i * H_DIM);
      const float4* b4 = (const float4*)ceb2;
      float acc = pmb[i];
      for (int k = 0; k < 256; ++k) {
        float4 w = w4[k], bb2 = b4[k];
        acc += w.x * bb2.x + w.y * bb2.y + w.z * bb2.z + w.w * bb2.w;
      }
      b32[i] = acc;
    } else {
      for (int i = t; i < H_DIM; i += 256) rtau[i] = 1.0f / tau[i];
    }
    return;
  }

  const float* in;
  u16* out;
  int chunk;
  if (b < 2048) {
    in = h; out = hb; chunk = b;
  } else if (b < 4096) {
    in = e; out = eb; chunk = b - 2048;
  } else if (b < 4224) {
    in = w1f; out = o1; chunk = b - 4096;
  } else if (b < 4352) {
    in = pmwf; out = o3; chunk = b - 4224;
  } else {
    in = wrecf; out = o4; chunk = b - 4352;
  }
  // 32KB chunk: 4 ushort8 outputs/thread; each from 2 adjacent float4 loads.
  const float4* in4 = (const float4*)in + (size_t)chunk * 2048;
  ushort8* out8 = (ushort8*)out + (size_t)chunk * 1024;
  float4 v[8];
#pragma unroll
  for (int g = 0; g < 4; ++g) {
    const int oi = g * 256 + t;
    v[2 * g] = in4[2 * oi];
    v[2 * g + 1] = in4[2 * oi + 1];
  }
#pragma unroll
  for (int g = 0; g < 4; ++g) {
    const int oi = g * 256 + t;
    ushort4 lo = cvt4(v[2 * g]), hi = cvt4(v[2 * g + 1]);
    ushort8 o;
    o[0] = lo.x; o[1] = lo.y; o[2] = lo.z; o[3] = lo.w;
    o[4] = hi.x; o[5] = hi.y; o[6] = hi.z; o[7] = hi.w;
    out8[oi] = o;
  }
}

// ---------------- W32 = pm_w @ ce_w2 (1024^3, r7-verified) ----------------------------------
__global__ __launch_bounds__(256) void w32_gemm(const u16* __restrict__ A,
                                                const u16* __restrict__ Wt,
                                                u16* __restrict__ C) {
  const int t = threadIdx.x;
  const int wv = t >> 6, l = t & 63;
  const int l15 = l & 15, lg = l >> 4;
  const int m0 = (blockIdx.x >> 4) * 64 + (wv >> 1) * 32;
  const int n0 = (blockIdx.x & 15) * 64 + (wv & 1) * 32;

  const u16* ap0 = A + (size_t)(m0 + l15) * H_DIM + lg * 8;
  const u16* ap1 = ap0 + 16 * H_DIM;
  const u16* bp0 = Wt + (size_t)(n0 + l15) * H_DIM + lg * 8;
  const u16* bp1 = bp0 + 16 * H_DIM;

  f32x4 acc[2][2] = {};
#pragma unroll
  for (int kt = 0; kt < 32; ++kt) {
    bf16x8 aF[2], bF[2];
    aF[0] = *(const bf16x8*)(ap0 + kt * 32);
    aF[1] = *(const bf16x8*)(ap1 + kt * 32);
    bF[0] = *(const bf16x8*)(bp0 + kt * 32);
    bF[1] = *(const bf16x8*)(bp1 + kt * 32);
#pragma unroll
    for (int mi = 0; mi < 2; ++mi)
#pragma unroll
      for (int ni = 0; ni < 2; ++ni)
        acc[mi][ni] =
            __builtin_amdgcn_mfma_f32_16x16x32_bf16(aF[mi], bF[ni], acc[mi][ni], 0, 0, 0);
  }
#pragma unroll
  for (int mi = 0; mi < 2; ++mi)
#pragma unroll
    for (int ni = 0; ni < 2; ++ni) {
      const int col = n0 + ni * 16 + l15;
#pragma unroll
      for (int j = 0; j < 4; ++j) {
        const int row = m0 + mi * 16 + lg * 4 + j;
        C[(size_t)row * H_DIM + col] = f2bf(acc[mi][ni][j]);
      }
    }
}

// ---------------- bf16-A 256x256 deep-pipelined GEMM (r4-verified + stage-first) ------------
// T3 recipe ordering: issue STAGE gloads at TOP of subtile (before ds_reads). Hazard window
// identical (gloads target slot (s-1)&3, whose reads completed before the barrier ending s-1);
// issue is ~200 cyc earlier, extending latency cover.
template <int MODE>  // 3: stage+vmcnt(8); 2: vmcnt(4); 1: vmcnt(0); 0: none
__device__ __forceinline__ void subtile_step(u16* shp, int slot, int slot3, int aoff, int boff,
                                             int wv, const u16*& pA0, const u16*& pA1,
                                             const u16*& pB0, const u16*& pB1,
                                             f32x4 (&acc)[8][4]) {
  if (MODE == 3) {
    u16* da = shp + slot3 * 16384 + wv * 1024;
    GLDS16(pA0, da); GLDS16(pA1, da + 512);
    u16* db = shp + slot3 * 16384 + 8192 + wv * 1024;
    GLDS16(pB0, db); GLDS16(pB1, db + 512);
    pA0 += 32; pA1 += 32; pB0 += 32; pB1 += 32;
  }
  const u16* Ab = shp + slot * 16384 + aoff;
  const u16* Bb = shp + slot * 16384 + 8192 + boff;
  bf16x8 aF[8], bF[4];
#pragma unroll
  for (int i = 0; i < 4; ++i) aF[i] = *(const bf16x8*)(Ab + i * 512);
#pragma unroll
  for (int i = 0; i < 4; ++i) bF[i] = *(const bf16x8*)(Bb + i * 512);
#pragma unroll
  for (int i = 4; i < 8; ++i) aF[i] = *(const bf16x8*)(Ab + i * 512);
  __builtin_amdgcn_s_setprio(1);
#pragma unroll
  for (int mf = 0; mf < 8; ++mf)
#pragma unroll
    for (int nf = 0; nf < 4; ++nf)
      acc[mf][nf] = __builtin_amdgcn_mfma_f32_16x16x32_bf16(aF[mf], bF[nf], acc[mf][nf], 0, 0, 0);
  __builtin_amdgcn_s_setprio(0);
  if (MODE == 3) asm volatile("s_waitcnt vmcnt(8)" ::: "memory");
  if (MODE == 2) asm volatile("s_waitcnt vmcnt(4)" ::: "memory");
  if (MODE == 1) asm volatile("s_waitcnt vmcnt(0)" ::: "memory");
  __builtin_amdgcn_s_barrier();
}

template <bool RELU, bool HASBIAS, typename OUT>
__global__ __launch_bounds__(512, 2) void gemm256(const u16* __restrict__ A,
                                                  const u16* __restrict__ W,
                                                  const float* __restrict__ bias,
                                                  OUT* __restrict__ C) {
  extern __shared__ u16 sh[];
  const int t = threadIdx.x;
  const int wv = t >> 6, l = t & 63;
  const int wm = wv >> 2, wn = wv & 3;
  const int l15 = l & 15, lg = l >> 4;

  const int bid = blockIdx.x;
  const int logical = (bid & 7) * 32 + (bid >> 3);
  const int m0 = (logical >> 2) * 256;
  const int n0 = (logical & 3) * 256;

  const int koff = (lg ^ ((l15 >> 1) & 3)) * 8;
  const int aoff = (wm * 128 + l15) * 32 + koff;
  const int boff = (wn * 64 + l15) * 32 + koff;

  const int rowst = wv * 32 + (l >> 2);
  const int ksl = ((l & 3) ^ ((l >> 3) & 3)) * 8;
  const u16* pA0 = A + (size_t)(m0 + rowst) * H_DIM + ksl;
  const u16* pA1 = pA0 + 16 * H_DIM;
  const u16* pB0 = W + (size_t)(n0 + rowst) * H_DIM + ksl;
  const u16* pB1 = pB0 + 16 * H_DIM;

  f32x4 acc[8][4] = {};

#pragma unroll
  for (int s = 0; s < 3; ++s) {
    u16* da = sh + s * 16384 + wv * 1024;
    GLDS16(pA0, da); GLDS16(pA1, da + 512);
    u16* db = sh + s * 16384 + 8192 + wv * 1024;
    GLDS16(pB0, db); GLDS16(pB1, db + 512);
    pA0 += 32; pA1 += 32; pB0 += 32; pB1 += 32;
  }
  asm volatile("s_waitcnt vmcnt(8)" ::: "memory");
  __builtin_amdgcn_s_barrier();

  for (int s = 0; s < 29; ++s)
    subtile_step<3>(sh, s & 3, (s + 3) & 3, aoff, boff, wv, pA0, pA1, pB0, pB1, acc);
  subtile_step<2>(sh, 1, 0, aoff, boff, wv, pA0, pA1, pB0, pB1, acc);
  subtile_step<1>(sh, 2, 0, aoff, boff, wv, pA0, pA1, pB0, pB1, acc);
  subtile_step<0>(sh, 3, 0, aoff, boff, wv, pA0, pA1, pB0, pB1, acc);

  float bv[4];
#pragma unroll
  for (int nf = 0; nf < 4; ++nf)
    bv[nf] = HASBIAS ? bias[n0 + wn * 64 + nf * 16 + l15] : 0.0f;
#pragma unroll
  for (int mf = 0; mf < 8; ++mf) {
#pragma unroll
    for (int nf = 0; nf < 4; ++nf) {
      const int col = n0 + wn * 64 + nf * 16 + l15;
#pragma unroll
      for (int j = 0; j < 4; ++j) {
        const int row = m0 + wm * 128 + mf * 16 + lg * 4 + j;
        float v = acc[mf][nf][j] + bv[nf];
        if (RELU) v = fmaxf(v, 0.0f);
        if constexpr (sizeof(OUT) == 2)
          C[(size_t)row * H_DIM + col] = (OUT)f2bf(v);
        else
          C[(size_t)row * H_DIM + col] = v;
      }
    }
  }
}

// ---------------- fused liquid-neuron update + LayerNorm (all-bf16 reads, r6-verified) ------
__global__ __launch_bounds__(256) void liquid_ln(const u16* __restrict__ hb,
                                                 const u16* __restrict__ pa,
                                                 const u16* __restrict__ ev,
                                                 const float* __restrict__ bias,
                                                 const float* __restrict__ rtau,
                                                 const float* __restrict__ decay,
                                                 const float* __restrict__ lnw,
                                                 const float* __restrict__ lnb,
                                                 float* __restrict__ out) {
  const int wv = threadIdx.x >> 6, l = threadIdx.x & 63;
  const int row = blockIdx.x * 4 + wv;
  const size_t rb = (size_t)row * H_DIM;

  float d[16];
  float s = 0.f, ss = 0.f;
#pragma unroll
  for (int c = 0; c < 2; ++c) {
    const int col = c * 512 + l * 8;
    float b8[8], r8[8], dc8[8];
    *(float4*)b8 = *(const float4*)(bias + col);
    *(float4*)(b8 + 4) = *(const float4*)(bias + col + 4);
    *(float4*)r8 = *(const float4*)(rtau + col);
    *(float4*)(r8 + 4) = *(const float4*)(rtau + col + 4);
    *(float4*)dc8 = *(const float4*)(decay + col);
    *(float4*)(dc8 + 4) = *(const float4*)(decay + col + 4);
    ushort8 hv = *(const ushort8*)(hb + rb + col);
    ushort8 pv = *(const ushort8*)(pa + rb + col);
    ushort8 evv = *(const ushort8*)(ev + rb + col);
#pragma unroll
    for (int j = 0; j < 8; ++j) {
      const float hf = bf2f(hv[j]);
      const float p = bf2f(pv[j]);
      const float e = bf2f(evv[j]);
      const float num = fmaf(-dc8[j], hf, fmaf(1.0f + p, e, b8[j]));
      const float val = num * (1.0f + __expf(-p)) * r8[j];
      d[c * 8 + j] = val;
      s += val;
      ss += val * val;
    }
  }
#pragma unroll
  for (int off = 32; off; off >>= 1) {
    s += __shfl_xor(s, off);
    ss += __shfl_xor(ss, off);
  }
  const float mu = s * (1.0f / H_DIM);
  const float var = ss * (1.0f / H_DIM) - mu * mu;
  const float rstd = rsqrtf(var + 1e-5f);

#pragma unroll
  for (int c = 0; c < 2; ++c) {
    const int col = c * 512 + l * 8;
    float w8[8], lb8[8], o[8];
    *(float4*)w8 = *(const float4*)(lnw + col);
    *(float4*)(w8 + 4) = *(const float4*)(lnw + col + 4);
    *(float4*)lb8 = *(const float4*)(lnb + col);
    *(float4*)(lb8 + 4) = *(const float4*)(lnb + col + 4);
#pragma unroll
    for (int j = 0; j < 8; ++j) o[j] = fmaf((d[c * 8 + j] - mu) * rstd, w8[j], lb8[j]);
    *(float4*)(out + rb + col) = *(float4*)o;
    *(float4*)(out + rb + col + 4) = *(float4*)(o + 4);
  }
}

extern "C" void kernel_launch(void* const* d_in, const int* in_sizes, int n_in,
                              void* d_out, int out_size, void* d_ws, size_t ws_size,
                              hipStream_t stream) {
  // setup_inputs order: t, h, e, W_rec, bias, tau, decay, ln_w, ln_b,
  //                     ce_w1, ce_b1, ce_w2, ce_b2, pm_w, pm_b
  const float* h = (const float*)d_in[1];
  const float* e = (const float*)d_in[2];
  const float* Wrec = (const float*)d_in[3];
  const float* bias = (const float*)d_in[4];
  const float* tau = (const float*)d_in[5];
  const float* decay = (const float*)d_in[6];
  const float* lnw = (const float*)d_in[7];
  const float* lnb = (const float*)d_in[8];
  const float* ce_w1 = (const float*)d_in[9];
  const float* ce_b1 = (const float*)d_in[10];
  const float* ce_w2 = (const float*)d_in[11];
  const float* ce_b2 = (const float*)d_in[12];
  const float* pm_w = (const float*)d_in[13];
  const float* pm_b = (const float*)d_in[14];
  float* out = (float*)d_out;

  char* ws = (char*)d_ws;
  const size_t MB = 1024 * 1024;
  // [0,2) w1b | [2,4) w2t | [4,6) w3b(pm_w) | [6,8) w4b(Wrec) | [8,10) W32b
  // [10,11) rtau @10MB, b32 @10MB+8KB | [12,44) hbf (live to ln) | [44,76) ebf
  // [76,108) t1 -> evb (t1 dead after Gpa) | [108,140) pab.  Peak 140 MB.
  u16* w1b = (u16*)(ws + 0 * MB);
  u16* w2t = (u16*)(ws + 2 * MB);
  u16* w3b = (u16*)(ws + 4 * MB);
  u16* w4b = (u16*)(ws + 6 * MB);
  u16* W32b = (u16*)(ws + 8 * MB);
  float* rtau = (float*)(ws + 10 * MB);
  float* b32 = (float*)(ws + 10 * MB + 8192);
  u16* hbf = (u16*)(ws + 12 * MB);
  u16* ebf = (u16*)(ws + 44 * MB);
  u16* t1 = (u16*)(ws + 76 * MB);
  u16* evb = (u16*)(ws + 76 * MB);  // over t1 (dead after Gpa; stream-serial)
  u16* pab = (u16*)(ws + 108 * MB);

  cvt_all<<<4741, 256, 0, stream>>>(h, e, ce_w1, pm_w, Wrec, hbf, ebf, w1b, w3b, w4b, tau, rtau,
                                    ce_w2, w2t, ce_b2, pm_b, b32);
  w32_gemm<<<256, 256, 0, stream>>>(w3b, w2t, W32b);

  const int LDS_BYTES = 131072;
  hipFuncSetAttribute((const void*)gemm256<true, true, u16>,
                      hipFuncAttributeMaxDynamicSharedMemorySize, LDS_BYTES);
  hipFuncSetAttribute((const void*)gemm256<false, true, u16>,
                      hipFuncAttributeMaxDynamicSharedMemorySize, LDS_BYTES);
  hipFuncSetAttribute((const void*)gemm256<false, false, u16>,
                      hipFuncAttributeMaxDynamicSharedMemorySize, LDS_BYTES);

  const int NWG = (B_DIM / 256) * (H_DIM / 256);  // 256 blocks = 1 per CU
  gemm256<true, true, u16><<<NWG, 512, LDS_BYTES, stream>>>(hbf, w1b, ce_b1, t1);
  gemm256<false, true, u16><<<NWG, 512, LDS_BYTES, stream>>>(t1, W32b, b32, pab);
  gemm256<false, false, u16><<<NWG, 512, LDS_BYTES, stream>>>(ebf, w4b, nullptr, evb);

  liquid_ln<<<B_DIM / 4, 256, 0, stream>>>(hbf, pab, evb, bias, rtau, decay, lnw, lnb, out);
}